// Round 7
// baseline (324.537 us; speedup 1.0000x reference)
//
#include <hip/hip_runtime.h>
#include <hip/hip_bf16.h>

#define FEATN 898
#define EMBD 128
#define KT_FULL 28          // 28 full k-tiles of 32 (896), tile 28 handles k=896..897
#define KT_ALL 29           // padded tiles in Wfrag
#define CBITS 8
#define CSZ 256             // nodes per coarse bucket
#define CAP2 12288          // per-bucket capacity (mean ~8183, +45 sigma)
#define EPB 8192            // edges per p1 block

typedef __bf16 bf16x8 __attribute__((ext_vector_type(8)));
typedef float f32x4 __attribute__((ext_vector_type(4)));
typedef unsigned short ushort8 __attribute__((ext_vector_type(8)));

__device__ inline unsigned short f2bf(float f) {
    unsigned int u = __float_as_uint(f);
    unsigned int r = u + 0x7fffu + ((u >> 16) & 1u);   // RNE
    return (unsigned short)(r >> 16);
}

__device__ inline unsigned int pk_bf2(float a, float b) {
    // packs two f32 -> two bf16 (RNE); compiler emits v_cvt_pk_bf16_f32
    __hip_bfloat162 h = __float22bfloat162_rn(make_float2(a, b));
    unsigned int r;
    __builtin_memcpy(&r, &h, 4);
    return r;
}

// ---------------- layout probe: int32 vs int64(lo,hi) storage of edge_index ----------------
__global__ void k_detect(const int* __restrict__ ei32, int* __restrict__ flag) {
    __shared__ int any;
    int t = threadIdx.x;
    if (t == 0) any = 0;
    __syncthreads();
    if (ei32[2 * t + 1] != 0) atomicOr(&any, 1);
    __syncthreads();
    if (t == 0) flag[0] = any;   // 1 = int32 layout, 0 = int64 layout
}

// ---------------- init: zero bucket tails + fc1 accumulator ----------------
__global__ void k_init(int* __restrict__ gtails, int nbc, float* __restrict__ accum) {
    int i = blockIdx.x * blockDim.x + threadIdx.x;
    if (i < nbc) gtails[i] = 0;
    if (i < 128) accum[i] = 0.f;
}

// ---------------- p1: counting-sort pass — per-block hist, reserve runs, write payloads ----------------
__global__ __launch_bounds__(256) void k_p1(const int* __restrict__ ei, int E, int N, int nbc,
                                            const int* __restrict__ flag,
                                            int* __restrict__ gtails, unsigned int* __restrict__ bb) {
    __shared__ int hist[256], curs[256];
    int t = threadIdx.x;
    hist[t] = 0;
    __syncthreads();
    int e0 = blockIdx.x * EPB;
    int f = flag[0];
#pragma unroll
    for (int i = 0; i < EPB / 256; ++i) {
        int e = e0 + i * 256 + t;
        if (e < E) {
            int d = f ? ei[(size_t)E + e] : ei[2 * ((size_t)E + e)];
            d = min(max(d, 0), N - 1);
            atomicAdd(&hist[d >> CBITS], 1);
        }
    }
    __syncthreads();
    if (t < nbc) curs[t] = (hist[t] > 0) ? atomicAdd(&gtails[t], hist[t]) : 0;
    __syncthreads();
#pragma unroll
    for (int i = 0; i < EPB / 256; ++i) {
        int e = e0 + i * 256 + t;
        if (e < E) {
            int s = f ? ei[e] : ei[2 * (size_t)e];
            int d = f ? ei[(size_t)E + e] : ei[2 * ((size_t)E + e)];
            s = min(max(s, 0), N - 1);
            d = min(max(d, 0), N - 1);
            int c = d >> CBITS;
            int pos = atomicAdd(&curs[c], 1);
            if (pos < CAP2) bb[(size_t)c * CAP2 + pos] = ((unsigned)s << CBITS) | (unsigned)(d & (CSZ - 1));
        }
    }
}

// ---------------- p1b: exclusive scan of bucket totals (incl. self loops) ----------------
__global__ void k_p1b(const int* __restrict__ gtails, int N, int nbc,
                      int* __restrict__ boff, int* __restrict__ rowoffN) {
    __shared__ int s[256];
    int t = threadIdx.x;
    int tot = 0;
    if (t < nbc) tot = min(gtails[t], CAP2) + min(CSZ, N - t * CSZ);
    s[t] = tot;
    __syncthreads();
    for (int o = 1; o < 256; o <<= 1) {
        int v = (t >= o) ? s[t - o] : 0;
        __syncthreads();
        s[t] += v;
        __syncthreads();
    }
    if (t < nbc) boff[t] = s[t] - tot;
    if (t == 255) rowoffN[0] = s[255];
}

// ---------------- p2: per-bucket CSR build in LDS, window-local writes ----------------
__global__ __launch_bounds__(256) void k_p2(const unsigned int* __restrict__ bb,
                                            const int* __restrict__ gtails, const int* __restrict__ boff,
                                            int N, int* __restrict__ rowoff, float* __restrict__ dinv,
                                            int* __restrict__ colidx) {
    __shared__ unsigned int stash[CAP2];     // 48 KB
    __shared__ int hist[CSZ], curs[CSZ], sc[CSZ];
    int b = blockIdx.x;
    int t = threadIdx.x;
    int node0 = b * CSZ;
    int nbn = min(CSZ, N - node0);
    int T = min(gtails[b], CAP2);
    hist[t] = 0;
    __syncthreads();
    for (int i = t; i < T; i += 256) {
        unsigned int u = bb[(size_t)b * CAP2 + i];
        stash[i] = u;
        atomicAdd(&hist[u & (CSZ - 1)], 1);
    }
    __syncthreads();
    int v = (t < nbn) ? hist[t] + 1 : 0;
    sc[t] = v;
    __syncthreads();
    for (int o = 1; o < 256; o <<= 1) {
        int x_ = (t >= o) ? sc[t - o] : 0;
        __syncthreads();
        sc[t] += x_;
        __syncthreads();
    }
    int base = boff[b];
    if (t < nbn) {
        int node = node0 + t;
        int ex = sc[t] - v;
        rowoff[node] = base + ex;
        dinv[node] = rsqrtf((float)(hist[t] + 1));
        colidx[base + ex] = node;            // self loop first
        curs[t] = ex + 1;
    }
    __syncthreads();
    for (int i = t; i < T; i += 256) {
        unsigned int u = stash[i];
        int slot = atomicAdd(&curs[u & (CSZ - 1)], 1);
        colidx[base + slot] = (int)(u >> CBITS);
    }
}

// ---------------- injected scalar: feat[i][0] = emb[poi[i>>7]][i&127] ----------------
__global__ void k_val(const float* __restrict__ x, const float* __restrict__ emb,
                      int N, float* __restrict__ valv) {
    int i = blockIdx.x * blockDim.x + threadIdx.x;
    if (i < N) {
        int r = i >> 7;
        int poi = (int)x[(size_t)r * FEATN];
        poi = min(max(poi, 0), N - 1);
        valv[i] = emb[(size_t)poi * EMBD + (i & 127)];
    }
}

// ---------------- Wfrag prep: W1[898][64] f32 -> fragment-order bf16, zero-padded ----------------
__global__ void k_prepW(const float* __restrict__ W1, unsigned short* __restrict__ Wf) {
    int id = blockIdx.x * 256 + threadIdx.x;
    if (id >= KT_ALL * 4 * 64 * 8) return;
    int e = id & 7;
    int l = (id >> 3) & 63;
    int nt = (id >> 9) & 3;
    int kt = id >> 11;
    int k = kt * 32 + (l >> 4) * 8 + e;
    int n = nt * 16 + (l & 15);
    float v = (k < FEATN) ? W1[(size_t)k * 64 + n] : 0.f;
    Wf[id] = f2bf(v);
}

// ---------------- GEMM1 via MFMA: 16 rows/block, in-block K-split x4, per-wave LDS staging ----------------
// Each wave stages its x k-tile (16 rows x 32 f32 -> bf16) via coalesced 128B/4-lane loads,
// no barriers in the main loop; one __syncthreads for the 4-way K reduction in LDS.
__global__ __launch_bounds__(256, 6) void k_gemm1m(const float* __restrict__ x,
                                                   const unsigned short* __restrict__ Wf,
                                                   const float* __restrict__ W1,
                                                   const float* __restrict__ valv,
                                                   const float* __restrict__ dinv, int N,
                                                   float* __restrict__ out) {
    __shared__ __align__(16) unsigned char smem[5120 + 4 * 16 * 66 * 4];  // 22016 B
    // stage: per-wave 1280B region: [16 rows][80B] (40 bf16/row, 80B stride spreads banks)
    // red:   f32 [4][16][66] at +5120
    float* red = (float*)(smem + 5120);
    int t = threadIdx.x;
    int w = t >> 6;
    int l = t & 63;
    int r0 = blockIdx.x * 16;

    // K quarters: {0..7, 8..15, 16..22, 23..28(incl tail)}
    int ktb = (w == 0) ? 0 : (w == 1) ? 8 : (w == 2) ? 16 : 23;
    int kte = (w == 0) ? 8 : (w == 1) ? 16 : (w == 2) ? 23 : 29;

    int srow = r0 + (l >> 2);
    if (srow >= N) srow = N - 1;                 // clamp stage reads; stores guarded later
    const float* px = x + (size_t)srow * FEATN;
    int c = l & 3;
    unsigned char* stW = smem + w * 1280 + (l >> 2) * 80 + c * 16;      // write slot
    unsigned char* stR = smem + w * 1280 + (l & 15) * 80 + (l >> 4) * 16; // read slot
    const ushort8* wfg = (const ushort8*)Wf;

    f32x4 acc[4];
#pragma unroll
    for (int nt = 0; nt < 4; ++nt) acc[nt] = (f32x4){0.f, 0.f, 0.f, 0.f};

    for (int kt = ktb; kt < kte; ++kt) {
        uint4 up;
        if (kt < KT_FULL) {
            const float* p = px + kt * 32 + c * 8;
            float2 a0 = ((const float2*)p)[0];
            float2 a1 = ((const float2*)p)[1];
            float2 a2 = ((const float2*)p)[2];
            float2 a3 = ((const float2*)p)[3];
            up.x = pk_bf2(a0.x, a0.y);
            up.y = pk_bf2(a1.x, a1.y);
            up.z = pk_bf2(a2.x, a2.y);
            up.w = pk_bf2(a3.x, a3.y);
            if (kt == 0 && c == 0) up.x &= 0xFFFF0000u;   // zero POI-id col; exact corr in epilogue
        } else {                                           // tail tile: k=896..897 only
            up.x = up.y = up.z = up.w = 0u;
            if (c == 0) {
                float2 q = *(const float2*)(px + 896);
                up.x = pk_bf2(q.x, q.y);
            }
        }
        *(uint4*)stW = up;                                 // ds_write_b128 (wave-private region)
        bf16x8 a;
        __builtin_memcpy(&a, stR, 16);                     // ds_read_b128 after lgkmcnt
#pragma unroll
        for (int nt = 0; nt < 4; ++nt) {
            bf16x8 b;
            ushort8 ub = wfg[(kt * 4 + nt) * 64 + l];      // L2-hot broadcast
            __builtin_memcpy(&b, &ub, 16);
            acc[nt] = __builtin_amdgcn_mfma_f32_16x16x32_bf16(a, b, acc[nt], 0, 0, 0);
        }
    }

    // K-reduce across the 4 waves
    int colb = l & 15;
    int rquad = l >> 4;
#pragma unroll
    for (int nt = 0; nt < 4; ++nt)
#pragma unroll
        for (int rg = 0; rg < 4; ++rg)
            red[((w * 16) + rquad * 4 + rg) * 66 + nt * 16 + colb] = acc[nt][rg];
    __syncthreads();

    int col = t & 63;
    int rb = t >> 6;
    float wcol = W1[col];                                  // W1 row 0
#pragma unroll
    for (int rr = 0; rr < 4; ++rr) {
        int r16 = rb * 4 + rr;
        float s_ = red[(0 * 16 + r16) * 66 + col] + red[(1 * 16 + r16) * 66 + col] +
                   red[(2 * 16 + r16) * 66 + col] + red[(3 * 16 + r16) * 66 + col];
        int row = r0 + r16;
        if (row < N)
            out[(size_t)row * 64 + col] = dinv[row] * (s_ + valv[row] * wcol);
    }
}

// ---------------- aggregation, 64 features: wave per node ----------------
template <int EPI>  // 0: leaky ; 1: leaky(t)+t
__global__ __launch_bounds__(256) void k_agg64(const float* __restrict__ hw, const int* __restrict__ rowoff,
                                               const int* __restrict__ colidx, const float* __restrict__ dinv,
                                               const float* __restrict__ bias, int N, float* __restrict__ out) {
    int w = threadIdx.x >> 6;
    int lane = threadIdx.x & 63;
    int v = blockIdx.x * 4 + w;
    if (v >= N) return;
    int beg = rowoff[v], end = rowoff[v + 1];
    float a0 = 0.f, a1 = 0.f, a2 = 0.f, a3 = 0.f;
    int i = beg;
    for (; i + 4 <= end; i += 4) {
        int u0 = colidx[i], u1 = colidx[i + 1], u2 = colidx[i + 2], u3 = colidx[i + 3];
        a0 += hw[(size_t)u0 * 64 + lane];
        a1 += hw[(size_t)u1 * 64 + lane];
        a2 += hw[(size_t)u2 * 64 + lane];
        a3 += hw[(size_t)u3 * 64 + lane];
    }
    for (; i < end; ++i) a0 += hw[(size_t)colidx[i] * 64 + lane];
    float t_ = dinv[v] * ((a0 + a1) + (a2 + a3)) + bias[lane];
    float r = (EPI == 0) ? (t_ >= 0.f ? t_ : 0.01f * t_) : (t_ >= 0.f ? 2.f * t_ : 1.01f * t_);
    out[(size_t)v * 64 + lane] = r;
}

// ---------------- aggregation, 32 features: half-wave per node ----------------
template <int EPI>
__global__ __launch_bounds__(256) void k_agg32(const float* __restrict__ hw, const int* __restrict__ rowoff,
                                               const int* __restrict__ colidx, const float* __restrict__ dinv,
                                               const float* __restrict__ bias, int N, float* __restrict__ out) {
    int sub = threadIdx.x >> 5;
    int lane = threadIdx.x & 31;
    int v = blockIdx.x * 8 + sub;
    if (v >= N) return;
    int beg = rowoff[v], end = rowoff[v + 1];
    float a0 = 0.f, a1 = 0.f, a2 = 0.f, a3 = 0.f;
    int i = beg;
    for (; i + 4 <= end; i += 4) {
        int u0 = colidx[i], u1 = colidx[i + 1], u2 = colidx[i + 2], u3 = colidx[i + 3];
        a0 += hw[(size_t)u0 * 32 + lane];
        a1 += hw[(size_t)u1 * 32 + lane];
        a2 += hw[(size_t)u2 * 32 + lane];
        a3 += hw[(size_t)u3 * 32 + lane];
    }
    for (; i < end; ++i) a0 += hw[(size_t)colidx[i] * 32 + lane];
    float t_ = dinv[v] * ((a0 + a1) + (a2 + a3)) + bias[lane];
    float r = (EPI == 0) ? (t_ >= 0.f ? t_ : 0.01f * t_) : (t_ >= 0.f ? 2.f * t_ : 1.01f * t_);
    out[(size_t)v * 32 + lane] = r;
}

// ---------------- small GEMM ----------------
template <int K, int C>
__global__ __launch_bounds__(256) void k_gemmS(const float* __restrict__ h, const float* __restrict__ W,
                                               const float* __restrict__ dinv, int N, float* __restrict__ out) {
    __shared__ float ws[K * C];
    for (int j = threadIdx.x; j < K * C; j += 256) ws[j] = W[j];
    __syncthreads();
    const int rpb = 256 / C;
    int lr = threadIdx.x / C;
    int col = threadIdx.x % C;
    int row = blockIdx.x * rpb + lr;
    if (row >= N) return;
    const float* hr = h + (size_t)row * K;
    float acc = 0.f;
#pragma unroll
    for (int k = 0; k < K; ++k) acc += hr[k] * ws[k * C + col];
    out[(size_t)row * C + col] = acc * dinv[row];
}

// ---------------- GEMM5 ----------------
__global__ __launch_bounds__(256) void k_gemm5(const float* __restrict__ h, const float* __restrict__ W5,
                                               const float* __restrict__ dinv, int N, float* __restrict__ out) {
    int sub = threadIdx.x >> 5;
    int lane = threadIdx.x & 31;
    int row = blockIdx.x * 8 + sub;
    if (row >= N) return;
    float p = h[(size_t)row * 32 + lane] * W5[lane];
#pragma unroll
    for (int o = 16; o > 0; o >>= 1) p += __shfl_down(p, o, 32);
    if (lane == 0) out[row] = p * dinv[row];
}

// ---------------- aggregation, 1 feature ----------------
__global__ void k_agg1f(const float* __restrict__ hw, const int* __restrict__ rowoff,
                        const int* __restrict__ colidx, const float* __restrict__ dinv,
                        const float* __restrict__ b5, int N, float* __restrict__ vvec) {
    int v = blockIdx.x * blockDim.x + threadIdx.x;
    if (v >= N) return;
    int beg = rowoff[v], end = rowoff[v + 1];
    float s = 0.f;
    for (int i = beg; i < end; ++i) s += hw[colidx[i]];
    float h = dinv[v] * s + b5[0];
    vvec[v] = h >= 0.f ? h : 0.01f * h;
}

// ---------------- fc1 partial ----------------
__global__ __launch_bounds__(128) void k_fc1(const float* __restrict__ vvec, const float* __restrict__ fc1W,
                                             int N, float* __restrict__ accum) {
    int o = threadIdx.x;
    int rpb = (N + gridDim.x - 1) / gridDim.x;
    int r0 = blockIdx.x * rpb;
    int r1 = r0 + rpb;
    if (r1 > N) r1 = N;
    float acc = 0.f;
    for (int r = r0; r < r1; ++r) acc += vvec[r] * fc1W[(size_t)r * 128 + o];
    atomicAdd(&accum[o], acc);
}

// ---------------- fc2 final ----------------
__global__ __launch_bounds__(128) void k_fc2(const float* __restrict__ accum, const float* __restrict__ fc1b,
                                             const float* __restrict__ fc2W, const float* __restrict__ fc2b,
                                             float* __restrict__ outp) {
    __shared__ float s1[128];
    int t = threadIdx.x;
    float h = accum[t] + fc1b[t];
    s1[t] = h > 0.f ? h : 0.f;
    __syncthreads();
    float acc = fc2b[t];
    for (int o = 0; o < 128; ++o) acc += s1[o] * fc2W[o * 128 + t];
    outp[t] = acc > 0.f ? acc : 0.f;
}

extern "C" void kernel_launch(void* const* d_in, const int* in_sizes, int n_in,
                              void* d_out, int out_size, void* d_ws, size_t ws_size,
                              hipStream_t stream) {
    const float* x = (const float*)d_in[0];
    const int* ei = (const int*)d_in[2];
    const float* emb = (const float*)d_in[3];
    const float* W1 = (const float*)d_in[4];
    const float* b1 = (const float*)d_in[5];
    const float* W2 = (const float*)d_in[6];
    const float* b2 = (const float*)d_in[7];
    const float* W3 = (const float*)d_in[8];
    const float* b3 = (const float*)d_in[9];
    const float* W4 = (const float*)d_in[10];
    const float* b4 = (const float*)d_in[11];
    const float* W5 = (const float*)d_in[12];
    const float* b5 = (const float*)d_in[13];
    const float* fc1W = (const float*)d_in[14];
    const float* fc1b = (const float*)d_in[15];
    const float* fc2W = (const float*)d_in[16];
    const float* fc2b = (const float*)d_in[17];

    int N = in_sizes[0] / FEATN;
    int E = in_sizes[2] / 2;
    int NNZ = E + N;
    int NBC = (N + CSZ - 1) / CSZ;      // coarse buckets of 256 nodes

    char* w = (char*)d_ws;
    auto alloc = [&](size_t bytes) {
        char* p = w;
        w += (bytes + 255) & ~(size_t)255;
        return p;
    };
    float* dinv   = (float*)alloc((size_t)N * 4);
    int*   rowoff = (int*)alloc((size_t)(N + 1) * 4);
    int*   colidx = (int*)alloc((size_t)NNZ * 4);
    float* valv   = (float*)alloc((size_t)N * 4);
    float* accum  = (float*)alloc(512);
    int*   flag   = (int*)alloc(256);
    int*   gtails = (int*)alloc((size_t)NBC * 4);
    int*   boff   = (int*)alloc((size_t)NBC * 4);
    unsigned int* bb = (unsigned int*)alloc((size_t)NBC * CAP2 * 4);
    unsigned short* Wf = (unsigned short*)alloc((size_t)KT_ALL * 4 * 64 * 8 * 2);
    float* bufA   = (float*)alloc((size_t)N * 64 * 4);
    float* bufB   = (float*)alloc((size_t)N * 64 * 4);
    float* vvec   = (float*)alloc((size_t)N * 4);

    int nb = (N + 255) / 256;

    k_detect<<<1, 256, 0, stream>>>(ei, flag);
    k_init<<<1, 256, 0, stream>>>(gtails, NBC, accum);
    k_p1<<<(E + EPB - 1) / EPB, 256, 0, stream>>>(ei, E, N, NBC, flag, gtails, bb);
    k_p1b<<<1, 256, 0, stream>>>(gtails, N, NBC, boff, rowoff + N);
    k_p2<<<NBC, 256, 0, stream>>>(bb, gtails, boff, N, rowoff, dinv, colidx);
    k_val<<<nb, 256, 0, stream>>>(x, emb, N, valv);
    k_prepW<<<(KT_ALL * 4 * 64 * 8 + 255) / 256, 256, 0, stream>>>(W1, Wf);

    k_gemm1m<<<(N + 15) / 16, 256, 0, stream>>>(x, Wf, W1, valv, dinv, N, bufA);
    k_agg64<0><<<(N + 3) / 4, 256, 0, stream>>>(bufA, rowoff, colidx, dinv, b1, N, bufB);

    k_gemmS<64, 32><<<(N + 7) / 8, 256, 0, stream>>>(bufB, W2, dinv, N, bufA);
    k_agg32<0><<<(N + 7) / 8, 256, 0, stream>>>(bufA, rowoff, colidx, dinv, b2, N, bufB);

    k_gemmS<32, 32><<<(N + 7) / 8, 256, 0, stream>>>(bufB, W3, dinv, N, bufA);
    k_agg32<1><<<(N + 7) / 8, 256, 0, stream>>>(bufA, rowoff, colidx, dinv, b3, N, bufB);

    k_gemmS<32, 32><<<(N + 7) / 8, 256, 0, stream>>>(bufB, W4, dinv, N, bufA);
    k_agg32<1><<<(N + 7) / 8, 256, 0, stream>>>(bufA, rowoff, colidx, dinv, b4, N, bufB);

    k_gemm5<<<(N + 7) / 8, 256, 0, stream>>>(bufB, W5, dinv, N, bufA);
    k_agg1f<<<nb, 256, 0, stream>>>(bufA, rowoff, colidx, dinv, b5, N, vvec);

    k_fc1<<<300, 128, 0, stream>>>(vvec, fc1W, N, accum);
    k_fc2<<<1, 128, 0, stream>>>(accum, fc1b, fc2W, fc2b, (float*)d_out);
}

// Round 8
// 322.326 us; speedup vs baseline: 1.0069x; 1.0069x over previous
//
#include <hip/hip_runtime.h>
#include <hip/hip_bf16.h>

#define FEATN 898
#define EMBD 128
#define KT_FULL 28          // 28 full k-tiles of 32 (896), tile 28 handles k=896..897
#define KT_ALL 29           // padded tiles in Wfrag
#define CH 8                // k-tiles per staged chunk
#define CBITS 8
#define CSZ 256             // nodes per coarse bucket
#define CAP2 12288          // per-bucket capacity (mean ~8183, +45 sigma)
#define EPB 4096            // edges per p1 block

typedef __bf16 bf16x8 __attribute__((ext_vector_type(8)));
typedef float f32x4 __attribute__((ext_vector_type(4)));
typedef unsigned short ushort8 __attribute__((ext_vector_type(8)));

__device__ inline unsigned short f2bf(float f) {
    unsigned int u = __float_as_uint(f);
    unsigned int r = u + 0x7fffu + ((u >> 16) & 1u);   // RNE
    return (unsigned short)(r >> 16);
}

__device__ inline unsigned int pk_bf2(float a, float b) {
    // packs two f32 -> two bf16 (RNE); low 16 bits = a
    __hip_bfloat162 h = __float22bfloat162_rn(make_float2(a, b));
    unsigned int r;
    __builtin_memcpy(&r, &h, 4);
    return r;
}

// ---------------- detect layout + zero gtails/accum (fused init) ----------------
__global__ void k_detect(const int* __restrict__ ei32, int* __restrict__ flag,
                         int* __restrict__ gtails, int nbc, float* __restrict__ accum) {
    __shared__ int any;
    int t = threadIdx.x;
    if (t == 0) any = 0;
    __syncthreads();
    if (ei32[2 * t + 1] != 0) atomicOr(&any, 1);
    for (int i = t; i < nbc; i += 256) gtails[i] = 0;
    if (t < 128) accum[t] = 0.f;
    __syncthreads();
    if (t == 0) flag[0] = any;   // 1 = int32 layout, 0 = int64 layout
}

// ---------------- p1: counting-sort pass — per-block hist, reserve runs, write payloads ----------------
__global__ __launch_bounds__(256) void k_p1(const int* __restrict__ ei, int E, int N, int nbc,
                                            const int* __restrict__ flag,
                                            int* __restrict__ gtails, unsigned int* __restrict__ bb) {
    __shared__ int hist[256], curs[256];
    int t = threadIdx.x;
    hist[t] = 0;
    __syncthreads();
    int e0 = blockIdx.x * EPB;
    int f = flag[0];
#pragma unroll
    for (int i = 0; i < EPB / 256; ++i) {
        int e = e0 + i * 256 + t;
        if (e < E) {
            int d = f ? ei[(size_t)E + e] : ei[2 * ((size_t)E + e)];
            d = min(max(d, 0), N - 1);
            atomicAdd(&hist[d >> CBITS], 1);
        }
    }
    __syncthreads();
    if (t < nbc) curs[t] = (hist[t] > 0) ? atomicAdd(&gtails[t], hist[t]) : 0;
    __syncthreads();
#pragma unroll
    for (int i = 0; i < EPB / 256; ++i) {
        int e = e0 + i * 256 + t;
        if (e < E) {
            int s = f ? ei[e] : ei[2 * (size_t)e];
            int d = f ? ei[(size_t)E + e] : ei[2 * ((size_t)E + e)];
            s = min(max(s, 0), N - 1);
            d = min(max(d, 0), N - 1);
            int c = d >> CBITS;
            int pos = atomicAdd(&curs[c], 1);
            if (pos < CAP2) bb[(size_t)c * CAP2 + pos] = ((unsigned)s << CBITS) | (unsigned)(d & (CSZ - 1));
        }
    }
}

// ---------------- p1b: exclusive scan of bucket totals (incl. self loops) ----------------
__global__ void k_p1b(const int* __restrict__ gtails, int N, int nbc,
                      int* __restrict__ boff, int* __restrict__ rowoffN) {
    __shared__ int s[256];
    int t = threadIdx.x;
    int tot = 0;
    if (t < nbc) tot = min(gtails[t], CAP2) + min(CSZ, N - t * CSZ);
    s[t] = tot;
    __syncthreads();
    for (int o = 1; o < 256; o <<= 1) {
        int v = (t >= o) ? s[t - o] : 0;
        __syncthreads();
        s[t] += v;
        __syncthreads();
    }
    if (t < nbc) boff[t] = s[t] - tot;
    if (t == 255) rowoffN[0] = s[255];
}

// ---------------- p2: per-bucket CSR build in LDS, window-local writes ----------------
__global__ __launch_bounds__(256) void k_p2(const unsigned int* __restrict__ bb,
                                            const int* __restrict__ gtails, const int* __restrict__ boff,
                                            int N, int* __restrict__ rowoff, float* __restrict__ dinv,
                                            int* __restrict__ colidx) {
    __shared__ unsigned int stash[CAP2];     // 48 KB
    __shared__ int hist[CSZ], curs[CSZ], sc[CSZ];
    int b = blockIdx.x;
    int t = threadIdx.x;
    int node0 = b * CSZ;
    int nbn = min(CSZ, N - node0);
    int T = min(gtails[b], CAP2);
    hist[t] = 0;
    __syncthreads();
    for (int i = t; i < T; i += 256) {
        unsigned int u = bb[(size_t)b * CAP2 + i];
        stash[i] = u;
        atomicAdd(&hist[u & (CSZ - 1)], 1);
    }
    __syncthreads();
    int v = (t < nbn) ? hist[t] + 1 : 0;
    sc[t] = v;
    __syncthreads();
    for (int o = 1; o < 256; o <<= 1) {
        int x_ = (t >= o) ? sc[t - o] : 0;
        __syncthreads();
        sc[t] += x_;
        __syncthreads();
    }
    int base = boff[b];
    if (t < nbn) {
        int node = node0 + t;
        int ex = sc[t] - v;
        rowoff[node] = base + ex;
        dinv[node] = rsqrtf((float)(hist[t] + 1));
        colidx[base + ex] = node;            // self loop first
        curs[t] = ex + 1;
    }
    __syncthreads();
    for (int i = t; i < T; i += 256) {
        unsigned int u = stash[i];
        int slot = atomicAdd(&curs[u & (CSZ - 1)], 1);
        colidx[base + slot] = (int)(u >> CBITS);
    }
}

// ---------------- injected scalar: feat[i][0] = emb[poi[i>>7]][i&127] ----------------
__global__ void k_val(const float* __restrict__ x, const float* __restrict__ emb,
                      int N, float* __restrict__ valv) {
    int i = blockIdx.x * blockDim.x + threadIdx.x;
    if (i < N) {
        int r = i >> 7;
        int poi = (int)x[(size_t)r * FEATN];
        poi = min(max(poi, 0), N - 1);
        valv[i] = emb[(size_t)poi * EMBD + (i & 127)];
    }
}

// ---------------- Wfrag prep: W1[898][64] f32 -> fragment-order bf16, zero-padded ----------------
__global__ void k_prepW(const float* __restrict__ W1, unsigned short* __restrict__ Wf) {
    int id = blockIdx.x * 256 + threadIdx.x;
    if (id >= KT_ALL * 4 * 64 * 8) return;
    int e = id & 7;
    int l = (id >> 3) & 63;
    int nt = (id >> 9) & 3;
    int kt = id >> 11;
    int k = kt * 32 + (l >> 4) * 8 + e;
    int n = nt * 16 + (l & 15);
    float v = (k < FEATN) ? W1[(size_t)k * 64 + n] : 0.f;
    Wf[id] = f2bf(v);
}

// ---------------- GEMM1 via MFMA: cooperative coalesced staging of x into A-fragment LDS ----------------
// Block = 64 rows, 4 waves; wave w owns rows w*16..w*16+15 across full K (no reduction).
// Stage pattern: 32 consecutive lanes read 1KB contiguous of ONE row -> 8x 1KB segments/pass.
__global__ __launch_bounds__(256) void k_gemm1m(const float* __restrict__ x,
                                                const unsigned short* __restrict__ Wf,
                                                const float* __restrict__ W1,
                                                const float* __restrict__ valv,
                                                const float* __restrict__ dinv, int N,
                                                float* __restrict__ out) {
    __shared__ unsigned short frag[4][CH][65][8];   // 33280 B; 65-lane stride spreads kt across banks
    int t = threadIdx.x;
    int w = t >> 6;
    int l = t & 63;
    int r0 = blockIdx.x * 64;
    int s = t & 31;          // staging slot within row-pass: kt=s>>2, kg=s&3
    int jrow = t >> 5;       // 0..7: row within pass
    const ushort8* wfg = (const ushort8*)Wf;

    f32x4 acc[4];
#pragma unroll
    for (int nt = 0; nt < 4; ++nt) acc[nt] = (f32x4){0.f, 0.f, 0.f, 0.f};

    for (int c0 = 0; c0 < KT_ALL; c0 += CH) {
        int nkt = min(CH, KT_ALL - c0);
        __syncthreads();                           // previous chunk's reads complete
        if (s < nkt * 4) {
            int ktl = s >> 2;
            int kg = s & 3;
            int gkt = c0 + ktl;
            int col0 = gkt * 32 + kg * 8;
#pragma unroll
            for (int p = 0; p < 8; ++p) {
                int j = p * 8 + jrow;
                int rg = r0 + j;
                if (rg >= N) rg = N - 1;           // clamp; stores guarded in epilogue
                const float* pr = x + (size_t)rg * FEATN + col0;
                uint4 up;
                if (gkt < KT_FULL) {
                    float2 a0 = ((const float2*)pr)[0];
                    float2 a1 = ((const float2*)pr)[1];
                    float2 a2 = ((const float2*)pr)[2];
                    float2 a3 = ((const float2*)pr)[3];
                    up.x = pk_bf2(a0.x, a0.y);
                    up.y = pk_bf2(a1.x, a1.y);
                    up.z = pk_bf2(a2.x, a2.y);
                    up.w = pk_bf2(a3.x, a3.y);
                    if (col0 == 0) up.x &= 0xFFFF0000u;   // zero POI-id col; exact corr in epilogue
                } else {                                   // tail tile: k=896..897 only
                    up.x = up.y = up.z = up.w = 0u;
                    if (kg == 0) {
                        float2 q = ((const float2*)pr)[0];
                        up.x = pk_bf2(q.x, q.y);
                    }
                }
                *(uint4*)&frag[j >> 4][ktl][kg * 16 + (j & 15)][0] = up;
            }
        }
        __syncthreads();
        for (int kt = 0; kt < nkt; ++kt) {
            bf16x8 a;
            __builtin_memcpy(&a, &frag[w][kt][l][0], 16);  // lane-contiguous ds_read_b128
            int gkt = c0 + kt;
#pragma unroll
            for (int nt = 0; nt < 4; ++nt) {
                bf16x8 b;
                ushort8 ub = wfg[(gkt * 4 + nt) * 64 + l]; // L2-hot broadcast
                __builtin_memcpy(&b, &ub, 16);
                acc[nt] = __builtin_amdgcn_mfma_f32_16x16x32_bf16(a, b, acc[nt], 0, 0, 0);
            }
        }
    }

    // epilogue: C/D layout col=lane&15, row=(lane>>4)*4+reg
    int colb = l & 15;
    int rquad = l >> 4;
    int rowbase = r0 + w * 16 + rquad * 4;
    float dv[4], vv[4];
#pragma unroll
    for (int rg = 0; rg < 4; ++rg) {
        int row = rowbase + rg;
        int rc = (row < N) ? row : (N - 1);
        dv[rg] = dinv[rc];
        vv[rg] = valv[rc];
    }
#pragma unroll
    for (int nt = 0; nt < 4; ++nt) {
        int col = nt * 16 + colb;
        float wcol = W1[col];                      // W1 row 0
#pragma unroll
        for (int rg = 0; rg < 4; ++rg) {
            int row = rowbase + rg;
            if (row < N)
                out[(size_t)row * 64 + col] = dv[rg] * (acc[nt][rg] + vv[rg] * wcol);
        }
    }
}

// ---------------- aggregation, 64 features: wave per node ----------------
template <int EPI>  // 0: leaky ; 1: leaky(t)+t
__global__ __launch_bounds__(256) void k_agg64(const float* __restrict__ hw, const int* __restrict__ rowoff,
                                               const int* __restrict__ colidx, const float* __restrict__ dinv,
                                               const float* __restrict__ bias, int N, float* __restrict__ out) {
    int w = threadIdx.x >> 6;
    int lane = threadIdx.x & 63;
    int v = blockIdx.x * 4 + w;
    if (v >= N) return;
    int beg = rowoff[v], end = rowoff[v + 1];
    float a0 = 0.f, a1 = 0.f, a2 = 0.f, a3 = 0.f;
    int i = beg;
    for (; i + 4 <= end; i += 4) {
        int u0 = colidx[i], u1 = colidx[i + 1], u2 = colidx[i + 2], u3 = colidx[i + 3];
        a0 += hw[(size_t)u0 * 64 + lane];
        a1 += hw[(size_t)u1 * 64 + lane];
        a2 += hw[(size_t)u2 * 64 + lane];
        a3 += hw[(size_t)u3 * 64 + lane];
    }
    for (; i < end; ++i) a0 += hw[(size_t)colidx[i] * 64 + lane];
    float t_ = dinv[v] * ((a0 + a1) + (a2 + a3)) + bias[lane];
    float r = (EPI == 0) ? (t_ >= 0.f ? t_ : 0.01f * t_) : (t_ >= 0.f ? 2.f * t_ : 1.01f * t_);
    out[(size_t)v * 64 + lane] = r;
}

// ---------------- aggregation, 32 features: half-wave per node ----------------
template <int EPI>
__global__ __launch_bounds__(256) void k_agg32(const float* __restrict__ hw, const int* __restrict__ rowoff,
                                               const int* __restrict__ colidx, const float* __restrict__ dinv,
                                               const float* __restrict__ bias, int N, float* __restrict__ out) {
    int sub = threadIdx.x >> 5;
    int lane = threadIdx.x & 31;
    int v = blockIdx.x * 8 + sub;
    if (v >= N) return;
    int beg = rowoff[v], end = rowoff[v + 1];
    float a0 = 0.f, a1 = 0.f, a2 = 0.f, a3 = 0.f;
    int i = beg;
    for (; i + 4 <= end; i += 4) {
        int u0 = colidx[i], u1 = colidx[i + 1], u2 = colidx[i + 2], u3 = colidx[i + 3];
        a0 += hw[(size_t)u0 * 32 + lane];
        a1 += hw[(size_t)u1 * 32 + lane];
        a2 += hw[(size_t)u2 * 32 + lane];
        a3 += hw[(size_t)u3 * 32 + lane];
    }
    for (; i < end; ++i) a0 += hw[(size_t)colidx[i] * 32 + lane];
    float t_ = dinv[v] * ((a0 + a1) + (a2 + a3)) + bias[lane];
    float r = (EPI == 0) ? (t_ >= 0.f ? t_ : 0.01f * t_) : (t_ >= 0.f ? 2.f * t_ : 1.01f * t_);
    out[(size_t)v * 32 + lane] = r;
}

// ---------------- small GEMM ----------------
template <int K, int C>
__global__ __launch_bounds__(256) void k_gemmS(const float* __restrict__ h, const float* __restrict__ W,
                                               const float* __restrict__ dinv, int N, float* __restrict__ out) {
    __shared__ float ws[K * C];
    for (int j = threadIdx.x; j < K * C; j += 256) ws[j] = W[j];
    __syncthreads();
    const int rpb = 256 / C;
    int lr = threadIdx.x / C;
    int col = threadIdx.x % C;
    int row = blockIdx.x * rpb + lr;
    if (row >= N) return;
    const float* hr = h + (size_t)row * K;
    float acc = 0.f;
#pragma unroll
    for (int k = 0; k < K; ++k) acc += hr[k] * ws[k * C + col];
    out[(size_t)row * C + col] = acc * dinv[row];
}

// ---------------- GEMM5 ----------------
__global__ __launch_bounds__(256) void k_gemm5(const float* __restrict__ h, const float* __restrict__ W5,
                                               const float* __restrict__ dinv, int N, float* __restrict__ out) {
    int sub = threadIdx.x >> 5;
    int lane = threadIdx.x & 31;
    int row = blockIdx.x * 8 + sub;
    if (row >= N) return;
    float p = h[(size_t)row * 32 + lane] * W5[lane];
#pragma unroll
    for (int o = 16; o > 0; o >>= 1) p += __shfl_down(p, o, 32);
    if (lane == 0) out[row] = p * dinv[row];
}

// ---------------- aggregation, 1 feature ----------------
__global__ void k_agg1f(const float* __restrict__ hw, const int* __restrict__ rowoff,
                        const int* __restrict__ colidx, const float* __restrict__ dinv,
                        const float* __restrict__ b5, int N, float* __restrict__ vvec) {
    int v = blockIdx.x * blockDim.x + threadIdx.x;
    if (v >= N) return;
    int beg = rowoff[v], end = rowoff[v + 1];
    float s = 0.f;
    for (int i = beg; i < end; ++i) s += hw[colidx[i]];
    float h = dinv[v] * s + b5[0];
    vvec[v] = h >= 0.f ? h : 0.01f * h;
}

// ---------------- fc1 partial ----------------
__global__ __launch_bounds__(128) void k_fc1(const float* __restrict__ vvec, const float* __restrict__ fc1W,
                                             int N, float* __restrict__ accum) {
    int o = threadIdx.x;
    int rpb = (N + gridDim.x - 1) / gridDim.x;
    int r0 = blockIdx.x * rpb;
    int r1 = r0 + rpb;
    if (r1 > N) r1 = N;
    float acc = 0.f;
    for (int r = r0; r < r1; ++r) acc += vvec[r] * fc1W[(size_t)r * 128 + o];
    atomicAdd(&accum[o], acc);
}

// ---------------- fc2 final ----------------
__global__ __launch_bounds__(128) void k_fc2(const float* __restrict__ accum, const float* __restrict__ fc1b,
                                             const float* __restrict__ fc2W, const float* __restrict__ fc2b,
                                             float* __restrict__ outp) {
    __shared__ float s1[128];
    int t = threadIdx.x;
    float h = accum[t] + fc1b[t];
    s1[t] = h > 0.f ? h : 0.f;
    __syncthreads();
    float acc = fc2b[t];
    for (int o = 0; o < 128; ++o) acc += s1[o] * fc2W[o * 128 + t];
    outp[t] = acc > 0.f ? acc : 0.f;
}

extern "C" void kernel_launch(void* const* d_in, const int* in_sizes, int n_in,
                              void* d_out, int out_size, void* d_ws, size_t ws_size,
                              hipStream_t stream) {
    const float* x = (const float*)d_in[0];
    const int* ei = (const int*)d_in[2];
    const float* emb = (const float*)d_in[3];
    const float* W1 = (const float*)d_in[4];
    const float* b1 = (const float*)d_in[5];
    const float* W2 = (const float*)d_in[6];
    const float* b2 = (const float*)d_in[7];
    const float* W3 = (const float*)d_in[8];
    const float* b3 = (const float*)d_in[9];
    const float* W4 = (const float*)d_in[10];
    const float* b4 = (const float*)d_in[11];
    const float* W5 = (const float*)d_in[12];
    const float* b5 = (const float*)d_in[13];
    const float* fc1W = (const float*)d_in[14];
    const float* fc1b = (const float*)d_in[15];
    const float* fc2W = (const float*)d_in[16];
    const float* fc2b = (const float*)d_in[17];

    int N = in_sizes[0] / FEATN;
    int E = in_sizes[2] / 2;
    int NNZ = E + N;
    int NBC = (N + CSZ - 1) / CSZ;      // coarse buckets of 256 nodes

    char* w = (char*)d_ws;
    auto alloc = [&](size_t bytes) {
        char* p = w;
        w += (bytes + 255) & ~(size_t)255;
        return p;
    };
    float* dinv   = (float*)alloc((size_t)N * 4);
    int*   rowoff = (int*)alloc((size_t)(N + 1) * 4);
    int*   colidx = (int*)alloc((size_t)NNZ * 4);
    float* valv   = (float*)alloc((size_t)N * 4);
    float* accum  = (float*)alloc(512);
    int*   flag   = (int*)alloc(256);
    int*   gtails = (int*)alloc((size_t)NBC * 4);
    int*   boff   = (int*)alloc((size_t)NBC * 4);
    unsigned int* bb = (unsigned int*)alloc((size_t)NBC * CAP2 * 4);
    unsigned short* Wf = (unsigned short*)alloc((size_t)KT_ALL * 4 * 64 * 8 * 2);
    float* bufA   = (float*)alloc((size_t)N * 64 * 4);
    float* bufB   = (float*)alloc((size_t)N * 64 * 4);
    float* vvec   = (float*)alloc((size_t)N * 4);

    int nb = (N + 255) / 256;

    k_detect<<<1, 256, 0, stream>>>(ei, flag, gtails, NBC, accum);
    k_p1<<<(E + EPB - 1) / EPB, 256, 0, stream>>>(ei, E, N, NBC, flag, gtails, bb);
    k_p1b<<<1, 256, 0, stream>>>(gtails, N, NBC, boff, rowoff + N);
    k_p2<<<NBC, 256, 0, stream>>>(bb, gtails, boff, N, rowoff, dinv, colidx);
    k_val<<<nb, 256, 0, stream>>>(x, emb, N, valv);
    k_prepW<<<(KT_ALL * 4 * 64 * 8 + 255) / 256, 256, 0, stream>>>(W1, Wf);

    k_gemm1m<<<(N + 63) / 64, 256, 0, stream>>>(x, Wf, W1, valv, dinv, N, bufA);
    k_agg64<0><<<(N + 3) / 4, 256, 0, stream>>>(bufA, rowoff, colidx, dinv, b1, N, bufB);

    k_gemmS<64, 32><<<(N + 7) / 8, 256, 0, stream>>>(bufB, W2, dinv, N, bufA);
    k_agg32<0><<<(N + 7) / 8, 256, 0, stream>>>(bufA, rowoff, colidx, dinv, b2, N, bufB);

    k_gemmS<32, 32><<<(N + 7) / 8, 256, 0, stream>>>(bufB, W3, dinv, N, bufA);
    k_agg32<1><<<(N + 7) / 8, 256, 0, stream>>>(bufA, rowoff, colidx, dinv, b3, N, bufB);

    k_gemmS<32, 32><<<(N + 7) / 8, 256, 0, stream>>>(bufB, W4, dinv, N, bufA);
    k_agg32<1><<<(N + 7) / 8, 256, 0, stream>>>(bufA, rowoff, colidx, dinv, b4, N, bufB);

    k_gemm5<<<(N + 7) / 8, 256, 0, stream>>>(bufB, W5, dinv, N, bufA);
    k_agg1f<<<nb, 256, 0, stream>>>(bufA, rowoff, colidx, dinv, b5, N, vvec);

    k_fc1<<<300, 128, 0, stream>>>(vvec, fc1W, N, accum);
    k_fc2<<<1, 128, 0, stream>>>(accum, fc1b, fc2W, fc2b, (float*)d_out);
}

// Round 9
// 266.377 us; speedup vs baseline: 1.2183x; 1.2100x over previous
//
#include <hip/hip_runtime.h>
#include <hip/hip_bf16.h>

#define FEATN 898
#define EMBD 128
#define KT_FULL 28          // 28 full k-tiles of 32 (896), tile 28 handles k=896..897
#define KT_ALL 29           // padded tiles in Wfrag
#define CH 8                // k-tiles per staged chunk
#define CBITS 8
#define CSZ 256             // nodes per coarse bucket
#define CAP2 12288          // per-bucket capacity (mean ~8183, +45 sigma)
#define EPB 4096            // edges per p1 block

typedef __bf16 bf16x8 __attribute__((ext_vector_type(8)));
typedef float f32x4 __attribute__((ext_vector_type(4)));
typedef unsigned short ushort8 __attribute__((ext_vector_type(8)));

__device__ inline unsigned short f2bf(float f) {
    unsigned int u = __float_as_uint(f);
    unsigned int r = u + 0x7fffu + ((u >> 16) & 1u);   // RNE
    return (unsigned short)(r >> 16);
}
__device__ inline float bfh(unsigned short u) {
    return __uint_as_float((unsigned int)u << 16);
}
__device__ inline unsigned int pk_bf2(float a, float b) {
    __hip_bfloat162 h = __float22bfloat162_rn(make_float2(a, b));
    unsigned int r;
    __builtin_memcpy(&r, &h, 4);
    return r;
}

// ---------------- detect layout + zero gtails/accum (fused init) ----------------
__global__ void k_detect(const int* __restrict__ ei32, int* __restrict__ flag,
                         int* __restrict__ gtails, int nbc, float* __restrict__ accum) {
    __shared__ int any;
    int t = threadIdx.x;
    if (t == 0) any = 0;
    __syncthreads();
    if (ei32[2 * t + 1] != 0) atomicOr(&any, 1);
    for (int i = t; i < nbc; i += 256) gtails[i] = 0;
    if (t < 128) accum[t] = 0.f;
    __syncthreads();
    if (t == 0) flag[0] = any;   // 1 = int32 layout, 0 = int64 layout
}

// ---------------- p1: counting-sort pass ----------------
__global__ __launch_bounds__(256) void k_p1(const int* __restrict__ ei, int E, int N, int nbc,
                                            const int* __restrict__ flag,
                                            int* __restrict__ gtails, unsigned int* __restrict__ bb) {
    __shared__ int hist[256], curs[256];
    int t = threadIdx.x;
    hist[t] = 0;
    __syncthreads();
    int e0 = blockIdx.x * EPB;
    int f = flag[0];
#pragma unroll
    for (int i = 0; i < EPB / 256; ++i) {
        int e = e0 + i * 256 + t;
        if (e < E) {
            int d = f ? ei[(size_t)E + e] : ei[2 * ((size_t)E + e)];
            d = min(max(d, 0), N - 1);
            atomicAdd(&hist[d >> CBITS], 1);
        }
    }
    __syncthreads();
    if (t < nbc) curs[t] = (hist[t] > 0) ? atomicAdd(&gtails[t], hist[t]) : 0;
    __syncthreads();
#pragma unroll
    for (int i = 0; i < EPB / 256; ++i) {
        int e = e0 + i * 256 + t;
        if (e < E) {
            int s = f ? ei[e] : ei[2 * (size_t)e];
            int d = f ? ei[(size_t)E + e] : ei[2 * ((size_t)E + e)];
            s = min(max(s, 0), N - 1);
            d = min(max(d, 0), N - 1);
            int c = d >> CBITS;
            int pos = atomicAdd(&curs[c], 1);
            if (pos < CAP2) bb[(size_t)c * CAP2 + pos] = ((unsigned)s << CBITS) | (unsigned)(d & (CSZ - 1));
        }
    }
}

// ---------------- p1b: exclusive scan of bucket totals (incl. self loops) ----------------
__global__ void k_p1b(const int* __restrict__ gtails, int N, int nbc,
                      int* __restrict__ boff, int* __restrict__ rowoffN) {
    __shared__ int s[256];
    int t = threadIdx.x;
    int tot = 0;
    if (t < nbc) tot = min(gtails[t], CAP2) + min(CSZ, N - t * CSZ);
    s[t] = tot;
    __syncthreads();
    for (int o = 1; o < 256; o <<= 1) {
        int v = (t >= o) ? s[t - o] : 0;
        __syncthreads();
        s[t] += v;
        __syncthreads();
    }
    if (t < nbc) boff[t] = s[t] - tot;
    if (t == 255) rowoffN[0] = s[255];
}

// ---------------- p2: per-bucket CSR build in LDS ----------------
__global__ __launch_bounds__(256) void k_p2(const unsigned int* __restrict__ bb,
                                            const int* __restrict__ gtails, const int* __restrict__ boff,
                                            int N, int* __restrict__ rowoff, float* __restrict__ dinv,
                                            int* __restrict__ colidx) {
    __shared__ unsigned int stash[CAP2];     // 48 KB
    __shared__ int hist[CSZ], curs[CSZ], sc[CSZ];
    int b = blockIdx.x;
    int t = threadIdx.x;
    int node0 = b * CSZ;
    int nbn = min(CSZ, N - node0);
    int T = min(gtails[b], CAP2);
    hist[t] = 0;
    __syncthreads();
    for (int i = t; i < T; i += 256) {
        unsigned int u = bb[(size_t)b * CAP2 + i];
        stash[i] = u;
        atomicAdd(&hist[u & (CSZ - 1)], 1);
    }
    __syncthreads();
    int v = (t < nbn) ? hist[t] + 1 : 0;
    sc[t] = v;
    __syncthreads();
    for (int o = 1; o < 256; o <<= 1) {
        int x_ = (t >= o) ? sc[t - o] : 0;
        __syncthreads();
        sc[t] += x_;
        __syncthreads();
    }
    int base = boff[b];
    if (t < nbn) {
        int node = node0 + t;
        int ex = sc[t] - v;
        rowoff[node] = base + ex;
        dinv[node] = rsqrtf((float)(hist[t] + 1));
        colidx[base + ex] = node;            // self loop first
        curs[t] = ex + 1;
    }
    __syncthreads();
    for (int i = t; i < T; i += 256) {
        unsigned int u = stash[i];
        int slot = atomicAdd(&curs[u & (CSZ - 1)], 1);
        colidx[base + slot] = (int)(u >> CBITS);
    }
}

// ---------------- injected scalar: feat[i][0] = emb[poi[i>>7]][i&127] ----------------
__global__ void k_val(const float* __restrict__ x, const float* __restrict__ emb,
                      int N, float* __restrict__ valv) {
    int i = blockIdx.x * blockDim.x + threadIdx.x;
    if (i < N) {
        int r = i >> 7;
        int poi = (int)x[(size_t)r * FEATN];
        poi = min(max(poi, 0), N - 1);
        valv[i] = emb[(size_t)poi * EMBD + (i & 127)];
    }
}

// ---------------- Wfrag prep ----------------
__global__ void k_prepW(const float* __restrict__ W1, unsigned short* __restrict__ Wf) {
    int id = blockIdx.x * 256 + threadIdx.x;
    if (id >= KT_ALL * 4 * 64 * 8) return;
    int e = id & 7;
    int l = (id >> 3) & 63;
    int nt = (id >> 9) & 3;
    int kt = id >> 11;
    int k = kt * 32 + (l >> 4) * 8 + e;
    int n = nt * 16 + (l & 15);
    float v = (k < FEATN) ? W1[(size_t)k * 64 + n] : 0.f;
    Wf[id] = f2bf(v);
}

// ---------------- GEMM1 via MFMA: cooperative coalesced staging; bf16 output ----------------
__global__ __launch_bounds__(256) void k_gemm1m(const float* __restrict__ x,
                                                const unsigned short* __restrict__ Wf,
                                                const float* __restrict__ W1,
                                                const float* __restrict__ valv,
                                                const float* __restrict__ dinv, int N,
                                                unsigned short* __restrict__ out) {
    __shared__ unsigned short frag[4][CH][65][8];   // 33280 B
    int t = threadIdx.x;
    int w = t >> 6;
    int l = t & 63;
    int r0 = blockIdx.x * 64;
    int s = t & 31;
    int jrow = t >> 5;
    const ushort8* wfg = (const ushort8*)Wf;

    f32x4 acc[4];
#pragma unroll
    for (int nt = 0; nt < 4; ++nt) acc[nt] = (f32x4){0.f, 0.f, 0.f, 0.f};

    for (int c0 = 0; c0 < KT_ALL; c0 += CH) {
        int nkt = min(CH, KT_ALL - c0);
        __syncthreads();
        if (s < nkt * 4) {
            int ktl = s >> 2;
            int kg = s & 3;
            int gkt = c0 + ktl;
            int col0 = gkt * 32 + kg * 8;
#pragma unroll
            for (int p = 0; p < 8; ++p) {
                int j = p * 8 + jrow;
                int rg = r0 + j;
                if (rg >= N) rg = N - 1;
                const float* pr = x + (size_t)rg * FEATN + col0;
                uint4 up;
                if (gkt < KT_FULL) {
                    float2 a0 = ((const float2*)pr)[0];
                    float2 a1 = ((const float2*)pr)[1];
                    float2 a2 = ((const float2*)pr)[2];
                    float2 a3 = ((const float2*)pr)[3];
                    up.x = pk_bf2(a0.x, a0.y);
                    up.y = pk_bf2(a1.x, a1.y);
                    up.z = pk_bf2(a2.x, a2.y);
                    up.w = pk_bf2(a3.x, a3.y);
                    if (col0 == 0) up.x &= 0xFFFF0000u;   // zero POI-id col
                } else {
                    up.x = up.y = up.z = up.w = 0u;
                    if (kg == 0) {
                        float2 q = ((const float2*)pr)[0];
                        up.x = pk_bf2(q.x, q.y);
                    }
                }
                *(uint4*)&frag[j >> 4][ktl][kg * 16 + (j & 15)][0] = up;
            }
        }
        __syncthreads();
        for (int kt = 0; kt < nkt; ++kt) {
            bf16x8 a;
            __builtin_memcpy(&a, &frag[w][kt][l][0], 16);
            int gkt = c0 + kt;
#pragma unroll
            for (int nt = 0; nt < 4; ++nt) {
                bf16x8 b;
                ushort8 ub = wfg[(gkt * 4 + nt) * 64 + l];
                __builtin_memcpy(&b, &ub, 16);
                acc[nt] = __builtin_amdgcn_mfma_f32_16x16x32_bf16(a, b, acc[nt], 0, 0, 0);
            }
        }
    }

    int colb = l & 15;
    int rquad = l >> 4;
    int rowbase = r0 + w * 16 + rquad * 4;
    float dv[4], vv[4];
#pragma unroll
    for (int rg = 0; rg < 4; ++rg) {
        int row = rowbase + rg;
        int rc = (row < N) ? row : (N - 1);
        dv[rg] = dinv[rc];
        vv[rg] = valv[rc];
    }
#pragma unroll
    for (int nt = 0; nt < 4; ++nt) {
        int col = nt * 16 + colb;
        float wcol = W1[col];
#pragma unroll
        for (int rg = 0; rg < 4; ++rg) {
            int row = rowbase + rg;
            if (row < N)
                out[(size_t)row * 64 + col] = f2bf(dv[rg] * (acc[nt][rg] + vv[rg] * wcol));
        }
    }
}

// ---------------- fused aggregation + next-layer GEMM ----------------
// t = dinv[v]*sum_{u} gin[u] + bias ; h = EPI(t) ; gout[v] = bf16(dinv[v]*(h @ W))
// IN=64: wave per node; IN=32: half-wave per node. ON=32 or 1 (f32 out).
template <int IN, int ON, int EPI>
__global__ __launch_bounds__(256) void k_fagg(const unsigned short* __restrict__ gin,
                                              const int* __restrict__ rowoff,
                                              const int* __restrict__ colidx,
                                              const float* __restrict__ dinv,
                                              const float* __restrict__ bias,
                                              const float* __restrict__ W, int N,
                                              unsigned short* __restrict__ gout,
                                              float* __restrict__ gout1) {
    constexpr int NPB = 256 / IN;
    __shared__ float ws[IN * ON];
    __shared__ float hb[NPB][IN + 1];
    for (int j = threadIdx.x; j < IN * ON; j += 256) ws[j] = W[j];
    __syncthreads();
    int slot = threadIdx.x / IN;
    int lane = threadIdx.x % IN;
    int v = blockIdx.x * NPB + slot;
    bool act = v < N;
    float dvv = 0.f;
    if (act) {
        int beg = rowoff[v], end = rowoff[v + 1];
        dvv = dinv[v];
        float a0 = 0.f, a1 = 0.f, a2 = 0.f, a3 = 0.f;
        int i = beg;
        for (; i + 4 <= end; i += 4) {
            int u0 = colidx[i], u1 = colidx[i + 1], u2 = colidx[i + 2], u3 = colidx[i + 3];
            a0 += bfh(gin[(size_t)u0 * IN + lane]);
            a1 += bfh(gin[(size_t)u1 * IN + lane]);
            a2 += bfh(gin[(size_t)u2 * IN + lane]);
            a3 += bfh(gin[(size_t)u3 * IN + lane]);
        }
        for (; i < end; ++i) a0 += bfh(gin[(size_t)colidx[i] * IN + lane]);
        float t_ = dvv * ((a0 + a1) + (a2 + a3)) + bias[lane];
        float h = (EPI == 0) ? (t_ >= 0.f ? t_ : 0.01f * t_) : (t_ >= 0.f ? 2.f * t_ : 1.01f * t_);
        hb[slot][lane] = h;                       // same-wave LDS; hw-ordered
    }
    if (act) {
        if (ON == 32) {
            int c = lane & 31;
            float acc = 0.f;
            if (IN == 64) {
                int k0 = (lane >> 5) * 32;
#pragma unroll
                for (int k = 0; k < 32; ++k) acc += hb[slot][k0 + k] * ws[(k0 + k) * 32 + c];
                acc += __shfl_xor(acc, 32, 64);   // combine the two k-halves
                if (lane < 32) gout[(size_t)v * 32 + c] = f2bf(dvv * acc);
            } else {
#pragma unroll
                for (int k = 0; k < 32; ++k) acc += hb[slot][k] * ws[k * 32 + c];
                gout[(size_t)v * 32 + c] = f2bf(dvv * acc);
            }
        } else {                                   // ON==1, IN==32
            float p = hb[slot][lane] * ws[lane];
#pragma unroll
            for (int o = 16; o > 0; o >>= 1) p += __shfl_down(p, o, 32);
            if (lane == 0) gout1[v] = dvv * p;
        }
    }
}

// ---------------- aggregation, 1 feature (layer 5) ----------------
__global__ void k_agg1f(const float* __restrict__ hw, const int* __restrict__ rowoff,
                        const int* __restrict__ colidx, const float* __restrict__ dinv,
                        const float* __restrict__ b5, int N, float* __restrict__ vvec) {
    int v = blockIdx.x * blockDim.x + threadIdx.x;
    if (v >= N) return;
    int beg = rowoff[v], end = rowoff[v + 1];
    float s = 0.f;
    for (int i = beg; i < end; ++i) s += hw[colidx[i]];
    float h = dinv[v] * s + b5[0];
    vvec[v] = h >= 0.f ? h : 0.01f * h;
}

// ---------------- fc1 partial ----------------
__global__ __launch_bounds__(128) void k_fc1(const float* __restrict__ vvec, const float* __restrict__ fc1W,
                                             int N, float* __restrict__ accum) {
    int o = threadIdx.x;
    int rpb = (N + gridDim.x - 1) / gridDim.x;
    int r0 = blockIdx.x * rpb;
    int r1 = r0 + rpb;
    if (r1 > N) r1 = N;
    float acc = 0.f;
    for (int r = r0; r < r1; ++r) acc += vvec[r] * fc1W[(size_t)r * 128 + o];
    atomicAdd(&accum[o], acc);
}

// ---------------- fc2 final ----------------
__global__ __launch_bounds__(128) void k_fc2(const float* __restrict__ accum, const float* __restrict__ fc1b,
                                             const float* __restrict__ fc2W, const float* __restrict__ fc2b,
                                             float* __restrict__ outp) {
    __shared__ float s1[128];
    int t = threadIdx.x;
    float h = accum[t] + fc1b[t];
    s1[t] = h > 0.f ? h : 0.f;
    __syncthreads();
    float acc = fc2b[t];
    for (int o = 0; o < 128; ++o) acc += s1[o] * fc2W[o * 128 + t];
    outp[t] = acc > 0.f ? acc : 0.f;
}

extern "C" void kernel_launch(void* const* d_in, const int* in_sizes, int n_in,
                              void* d_out, int out_size, void* d_ws, size_t ws_size,
                              hipStream_t stream) {
    const float* x = (const float*)d_in[0];
    const int* ei = (const int*)d_in[2];
    const float* emb = (const float*)d_in[3];
    const float* W1 = (const float*)d_in[4];
    const float* b1 = (const float*)d_in[5];
    const float* W2 = (const float*)d_in[6];
    const float* b2 = (const float*)d_in[7];
    const float* W3 = (const float*)d_in[8];
    const float* b3 = (const float*)d_in[9];
    const float* W4 = (const float*)d_in[10];
    const float* b4 = (const float*)d_in[11];
    const float* W5 = (const float*)d_in[12];
    const float* b5 = (const float*)d_in[13];
    const float* fc1W = (const float*)d_in[14];
    const float* fc1b = (const float*)d_in[15];
    const float* fc2W = (const float*)d_in[16];
    const float* fc2b = (const float*)d_in[17];

    int N = in_sizes[0] / FEATN;
    int E = in_sizes[2] / 2;
    int NNZ = E + N;
    int NBC = (N + CSZ - 1) / CSZ;

    char* w = (char*)d_ws;
    auto alloc = [&](size_t bytes) {
        char* p = w;
        w += (bytes + 255) & ~(size_t)255;
        return p;
    };
    float* dinv   = (float*)alloc((size_t)N * 4);
    int*   rowoff = (int*)alloc((size_t)(N + 1) * 4);
    int*   colidx = (int*)alloc((size_t)NNZ * 4);
    float* valv   = (float*)alloc((size_t)N * 4);
    float* accum  = (float*)alloc(512);
    int*   flag   = (int*)alloc(256);
    int*   gtails = (int*)alloc((size_t)NBC * 4);
    int*   boff   = (int*)alloc((size_t)NBC * 4);
    unsigned int* bb = (unsigned int*)alloc((size_t)NBC * CAP2 * 4);
    unsigned short* Wf = (unsigned short*)alloc((size_t)KT_ALL * 4 * 64 * 8 * 2);
    unsigned short* g1 = (unsigned short*)alloc((size_t)N * 64 * 2);
    unsigned short* g2 = (unsigned short*)alloc((size_t)N * 32 * 2);
    unsigned short* g3 = (unsigned short*)alloc((size_t)N * 32 * 2);
    float* g5     = (float*)alloc((size_t)N * 4);
    float* vvec   = (float*)alloc((size_t)N * 4);

    int nb = (N + 255) / 256;

    k_detect<<<1, 256, 0, stream>>>(ei, flag, gtails, NBC, accum);
    k_p1<<<(E + EPB - 1) / EPB, 256, 0, stream>>>(ei, E, N, NBC, flag, gtails, bb);
    k_p1b<<<1, 256, 0, stream>>>(gtails, N, NBC, boff, rowoff + N);
    k_p2<<<NBC, 256, 0, stream>>>(bb, gtails, boff, N, rowoff, dinv, colidx);
    k_val<<<nb, 256, 0, stream>>>(x, emb, N, valv);
    k_prepW<<<(KT_ALL * 4 * 64 * 8 + 255) / 256, 256, 0, stream>>>(W1, Wf);

    k_gemm1m<<<(N + 63) / 64, 256, 0, stream>>>(x, Wf, W1, valv, dinv, N, g1);

    // layer1 agg + W2 ; layer2 agg + W3 ; layer3 agg(+res) + W4 ; layer4 agg(+res) + W5
    k_fagg<64, 32, 0><<<(N + 3) / 4, 256, 0, stream>>>(g1, rowoff, colidx, dinv, b1, W2, N, g2, nullptr);
    k_fagg<32, 32, 0><<<(N + 7) / 8, 256, 0, stream>>>(g2, rowoff, colidx, dinv, b2, W3, N, g3, nullptr);
    k_fagg<32, 32, 1><<<(N + 7) / 8, 256, 0, stream>>>(g3, rowoff, colidx, dinv, b3, W4, N, g2, nullptr);
    k_fagg<32, 1, 1><<<(N + 7) / 8, 256, 0, stream>>>(g2, rowoff, colidx, dinv, b4, W5, N, nullptr, g5);

    k_agg1f<<<nb, 256, 0, stream>>>(g5, rowoff, colidx, dinv, b5, N, vvec);

    k_fc1<<<300, 128, 0, stream>>>(vvec, fc1W, N, accum);
    k_fc2<<<1, 128, 0, stream>>>(accum, fc1b, fc2W, fc2b, (float*)d_out);
}

// Round 10
// 266.015 us; speedup vs baseline: 1.2200x; 1.0014x over previous
//
#include <hip/hip_runtime.h>
#include <hip/hip_bf16.h>

#define FEATN 898
#define EMBD 128
#define KT_FULL 28          // 28 full k-tiles of 32 (896), tile 28 handles k=896..897
#define KT_ALL 29           // padded tiles in Wfrag
#define CH 4                // k-tiles per staged chunk (both operands in LDS)
#define CBITS 8
#define CSZ 256             // nodes per coarse bucket
#define CAP2 12288          // per-bucket capacity (mean ~8183, +45 sigma)
#define EPB 4096            // edges per p1 block

typedef __bf16 bf16x8 __attribute__((ext_vector_type(8)));
typedef float f32x4 __attribute__((ext_vector_type(4)));
typedef unsigned short ushort8 __attribute__((ext_vector_type(8)));

__device__ inline unsigned short f2bf(float f) {
    unsigned int u = __float_as_uint(f);
    unsigned int r = u + 0x7fffu + ((u >> 16) & 1u);   // RNE
    return (unsigned short)(r >> 16);
}
__device__ inline float bfh(unsigned short u) {
    return __uint_as_float((unsigned int)u << 16);
}
__device__ inline unsigned int pk_bf2(float a, float b) {
    __hip_bfloat162 h = __float22bfloat162_rn(make_float2(a, b));
    unsigned int r;
    __builtin_memcpy(&r, &h, 4);
    return r;
}

// ---------------- detect layout + zero gtails/accum (fused init) ----------------
__global__ void k_detect(const int* __restrict__ ei32, int* __restrict__ flag,
                         int* __restrict__ gtails, int nbc, float* __restrict__ accum) {
    __shared__ int any;
    int t = threadIdx.x;
    if (t == 0) any = 0;
    __syncthreads();
    if (ei32[2 * t + 1] != 0) atomicOr(&any, 1);
    for (int i = t; i < nbc; i += 256) gtails[i] = 0;
    if (t < 128) accum[t] = 0.f;
    __syncthreads();
    if (t == 0) flag[0] = any;   // 1 = int32 layout, 0 = int64 layout
}

// ---------------- p1: counting-sort pass ----------------
__global__ __launch_bounds__(256) void k_p1(const int* __restrict__ ei, int E, int N, int nbc,
                                            const int* __restrict__ flag,
                                            int* __restrict__ gtails, unsigned int* __restrict__ bb) {
    __shared__ int hist[256], curs[256];
    int t = threadIdx.x;
    hist[t] = 0;
    __syncthreads();
    int e0 = blockIdx.x * EPB;
    int f = flag[0];
#pragma unroll
    for (int i = 0; i < EPB / 256; ++i) {
        int e = e0 + i * 256 + t;
        if (e < E) {
            int d = f ? ei[(size_t)E + e] : ei[2 * ((size_t)E + e)];
            d = min(max(d, 0), N - 1);
            atomicAdd(&hist[d >> CBITS], 1);
        }
    }
    __syncthreads();
    if (t < nbc) curs[t] = (hist[t] > 0) ? atomicAdd(&gtails[t], hist[t]) : 0;
    __syncthreads();
#pragma unroll
    for (int i = 0; i < EPB / 256; ++i) {
        int e = e0 + i * 256 + t;
        if (e < E) {
            int s = f ? ei[e] : ei[2 * (size_t)e];
            int d = f ? ei[(size_t)E + e] : ei[2 * ((size_t)E + e)];
            s = min(max(s, 0), N - 1);
            d = min(max(d, 0), N - 1);
            int c = d >> CBITS;
            int pos = atomicAdd(&curs[c], 1);
            if (pos < CAP2) bb[(size_t)c * CAP2 + pos] = ((unsigned)s << CBITS) | (unsigned)(d & (CSZ - 1));
        }
    }
}

// ---------------- p1b: exclusive scan of bucket totals (incl. self loops) ----------------
__global__ void k_p1b(const int* __restrict__ gtails, int N, int nbc,
                      int* __restrict__ boff, int* __restrict__ rowoffN) {
    __shared__ int s[256];
    int t = threadIdx.x;
    int tot = 0;
    if (t < nbc) tot = min(gtails[t], CAP2) + min(CSZ, N - t * CSZ);
    s[t] = tot;
    __syncthreads();
    for (int o = 1; o < 256; o <<= 1) {
        int v = (t >= o) ? s[t - o] : 0;
        __syncthreads();
        s[t] += v;
        __syncthreads();
    }
    if (t < nbc) boff[t] = s[t] - tot;
    if (t == 255) rowoffN[0] = s[255];
}

// ---------------- p2: per-bucket CSR build in LDS ----------------
__global__ __launch_bounds__(256) void k_p2(const unsigned int* __restrict__ bb,
                                            const int* __restrict__ gtails, const int* __restrict__ boff,
                                            int N, int* __restrict__ rowoff, float* __restrict__ dinv,
                                            int* __restrict__ colidx) {
    __shared__ unsigned int stash[CAP2];     // 48 KB
    __shared__ int hist[CSZ], curs[CSZ], sc[CSZ];
    int b = blockIdx.x;
    int t = threadIdx.x;
    int node0 = b * CSZ;
    int nbn = min(CSZ, N - node0);
    int T = min(gtails[b], CAP2);
    hist[t] = 0;
    __syncthreads();
    for (int i = t; i < T; i += 256) {
        unsigned int u = bb[(size_t)b * CAP2 + i];
        stash[i] = u;
        atomicAdd(&hist[u & (CSZ - 1)], 1);
    }
    __syncthreads();
    int v = (t < nbn) ? hist[t] + 1 : 0;
    sc[t] = v;
    __syncthreads();
    for (int o = 1; o < 256; o <<= 1) {
        int x_ = (t >= o) ? sc[t - o] : 0;
        __syncthreads();
        sc[t] += x_;
        __syncthreads();
    }
    int base = boff[b];
    if (t < nbn) {
        int node = node0 + t;
        int ex = sc[t] - v;
        rowoff[node] = base + ex;
        dinv[node] = rsqrtf((float)(hist[t] + 1));
        colidx[base + ex] = node;            // self loop first
        curs[t] = ex + 1;
    }
    __syncthreads();
    for (int i = t; i < T; i += 256) {
        unsigned int u = stash[i];
        int slot = atomicAdd(&curs[u & (CSZ - 1)], 1);
        colidx[base + slot] = (int)(u >> CBITS);
    }
}

// ---------------- injected scalar: feat[i][0] = emb[poi[i>>7]][i&127] ----------------
__global__ void k_val(const float* __restrict__ x, const float* __restrict__ emb,
                      int N, float* __restrict__ valv) {
    int i = blockIdx.x * blockDim.x + threadIdx.x;
    if (i < N) {
        int r = i >> 7;
        int poi = (int)x[(size_t)r * FEATN];
        poi = min(max(poi, 0), N - 1);
        valv[i] = emb[(size_t)poi * EMBD + (i & 127)];
    }
}

// ---------------- Wfrag prep ----------------
__global__ void k_prepW(const float* __restrict__ W1, unsigned short* __restrict__ Wf) {
    int id = blockIdx.x * 256 + threadIdx.x;
    if (id >= KT_ALL * 4 * 64 * 8) return;
    int e = id & 7;
    int l = (id >> 3) & 63;
    int nt = (id >> 9) & 3;
    int kt = id >> 11;
    int k = kt * 32 + (l >> 4) * 8 + e;
    int n = nt * 16 + (l & 15);
    float v = (k < FEATN) ? W1[(size_t)k * 64 + n] : 0.f;
    Wf[id] = f2bf(v);
}

// ---------------- GEMM1 via MFMA: BOTH operands staged through LDS ----------------
// Per chunk of 4 k-tiles: cooperative Wf stage (4x dwordx4/thread) + coalesced x stage
// (16 lanes read 512B contiguous of one row), then pure ds_read_b128 + MFMA inner loop.
__global__ __launch_bounds__(256, 4) void k_gemm1m(const float* __restrict__ x,
                                                   const unsigned short* __restrict__ Wf,
                                                   const float* __restrict__ W1,
                                                   const float* __restrict__ valv,
                                                   const float* __restrict__ dinv, int N,
                                                   unsigned short* __restrict__ out) {
    __shared__ unsigned short frag[4][CH][65][8];   // 16640 B (x A-fragments)
    __shared__ ushort8 wlds[CH * 4 * 64];           // 16384 B (W1 B-fragments)
    int t = threadIdx.x;
    int w = t >> 6;
    int l = t & 63;
    int r0 = blockIdx.x * 64;
    int sid = t & 15;           // (kt,kg) slot: kt=sid>>2, kg=sid&3
    int jrow = t >> 4;          // 0..15: row within 16-row pass
    const ushort8* wfg = (const ushort8*)Wf;

    f32x4 acc[4];
#pragma unroll
    for (int nt = 0; nt < 4; ++nt) acc[nt] = (f32x4){0.f, 0.f, 0.f, 0.f};

    for (int c0 = 0; c0 < KT_ALL; c0 += CH) {
        int nkt = min(CH, KT_ALL - c0);
        __syncthreads();                            // previous chunk's reads complete
        // stage Wf chunk (coalesced 16B/thread passes)
        for (int i = t; i < nkt * 256; i += 256) wlds[i] = wfg[(size_t)c0 * 256 + i];
        // stage x chunk: 16 consecutive lanes cover 512B of one row
        if (sid < nkt * 4) {
            int ktl = sid >> 2;
            int kg = sid & 3;
            int gkt = c0 + ktl;
            int col0 = gkt * 32 + kg * 8;
#pragma unroll
            for (int p = 0; p < 4; ++p) {
                int j = p * 16 + jrow;
                int rg = r0 + j;
                if (rg >= N) rg = N - 1;            // clamp; stores guarded in epilogue
                const float* pr = x + (size_t)rg * FEATN + col0;
                uint4 up;
                if (gkt < KT_FULL) {
                    float2 a0 = ((const float2*)pr)[0];
                    float2 a1 = ((const float2*)pr)[1];
                    float2 a2 = ((const float2*)pr)[2];
                    float2 a3 = ((const float2*)pr)[3];
                    up.x = pk_bf2(a0.x, a0.y);
                    up.y = pk_bf2(a1.x, a1.y);
                    up.z = pk_bf2(a2.x, a2.y);
                    up.w = pk_bf2(a3.x, a3.y);
                    if (col0 == 0) up.x &= 0xFFFF0000u;   // zero POI-id col; exact corr in epilogue
                } else {                                   // tail tile: k=896..897 only
                    up.x = up.y = up.z = up.w = 0u;
                    if (kg == 0) {
                        float2 q = *(const float2*)(x + (size_t)rg * FEATN + 896);
                        up.x = pk_bf2(q.x, q.y);
                    }
                }
                *(uint4*)&frag[j >> 4][ktl][kg * 16 + (j & 15)][0] = up;
            }
        }
        __syncthreads();
        for (int kt = 0; kt < nkt; ++kt) {
            bf16x8 a;
            __builtin_memcpy(&a, &frag[w][kt][l][0], 16);   // lane-contiguous ds_read_b128
#pragma unroll
            for (int nt = 0; nt < 4; ++nt) {
                bf16x8 b;
                ushort8 ub = wlds[(kt * 4 + nt) * 64 + l];  // lane-contiguous ds_read_b128
                __builtin_memcpy(&b, &ub, 16);
                acc[nt] = __builtin_amdgcn_mfma_f32_16x16x32_bf16(a, b, acc[nt], 0, 0, 0);
            }
        }
    }

    // epilogue: C/D layout col=lane&15, row=(lane>>4)*4+reg
    int colb = l & 15;
    int rquad = l >> 4;
    int rowbase = r0 + w * 16 + rquad * 4;
    float dv[4], vv[4];
#pragma unroll
    for (int rg = 0; rg < 4; ++rg) {
        int row = rowbase + rg;
        int rc = (row < N) ? row : (N - 1);
        dv[rg] = dinv[rc];
        vv[rg] = valv[rc];
    }
#pragma unroll
    for (int nt = 0; nt < 4; ++nt) {
        int col = nt * 16 + colb;
        float wcol = W1[col];
#pragma unroll
        for (int rg = 0; rg < 4; ++rg) {
            int row = rowbase + rg;
            if (row < N)
                out[(size_t)row * 64 + col] = f2bf(dv[rg] * (acc[nt][rg] + vv[rg] * wcol));
        }
    }
}

// ---------------- fused aggregation + next-layer GEMM ----------------
template <int IN, int ON, int EPI>
__global__ __launch_bounds__(256) void k_fagg(const unsigned short* __restrict__ gin,
                                              const int* __restrict__ rowoff,
                                              const int* __restrict__ colidx,
                                              const float* __restrict__ dinv,
                                              const float* __restrict__ bias,
                                              const float* __restrict__ W, int N,
                                              unsigned short* __restrict__ gout,
                                              float* __restrict__ gout1) {
    constexpr int NPB = 256 / IN;
    __shared__ float ws[IN * ON];
    __shared__ float hb[NPB][IN + 1];
    for (int j = threadIdx.x; j < IN * ON; j += 256) ws[j] = W[j];
    __syncthreads();
    int slot = threadIdx.x / IN;
    int lane = threadIdx.x % IN;
    int v = blockIdx.x * NPB + slot;
    bool act = v < N;
    float dvv = 0.f;
    if (act) {
        int beg = rowoff[v], end = rowoff[v + 1];
        dvv = dinv[v];
        float a0 = 0.f, a1 = 0.f, a2 = 0.f, a3 = 0.f;
        int i = beg;
        for (; i + 4 <= end; i += 4) {
            int u0 = colidx[i], u1 = colidx[i + 1], u2 = colidx[i + 2], u3 = colidx[i + 3];
            a0 += bfh(gin[(size_t)u0 * IN + lane]);
            a1 += bfh(gin[(size_t)u1 * IN + lane]);
            a2 += bfh(gin[(size_t)u2 * IN + lane]);
            a3 += bfh(gin[(size_t)u3 * IN + lane]);
        }
        for (; i < end; ++i) a0 += bfh(gin[(size_t)colidx[i] * IN + lane]);
        float t_ = dvv * ((a0 + a1) + (a2 + a3)) + bias[lane];
        float h = (EPI == 0) ? (t_ >= 0.f ? t_ : 0.01f * t_) : (t_ >= 0.f ? 2.f * t_ : 1.01f * t_);
        hb[slot][lane] = h;                       // same-wave LDS; hw-ordered
    }
    if (act) {
        if (ON == 32) {
            int c = lane & 31;
            float acc = 0.f;
            if (IN == 64) {
                int k0 = (lane >> 5) * 32;
#pragma unroll
                for (int k = 0; k < 32; ++k) acc += hb[slot][k0 + k] * ws[(k0 + k) * 32 + c];
                acc += __shfl_xor(acc, 32, 64);   // combine the two k-halves
                if (lane < 32) gout[(size_t)v * 32 + c] = f2bf(dvv * acc);
            } else {
#pragma unroll
                for (int k = 0; k < 32; ++k) acc += hb[slot][k] * ws[k * 32 + c];
                gout[(size_t)v * 32 + c] = f2bf(dvv * acc);
            }
        } else {                                   // ON==1, IN==32
            float p = hb[slot][lane] * ws[lane];
#pragma unroll
            for (int o = 16; o > 0; o >>= 1) p += __shfl_down(p, o, 32);
            if (lane == 0) gout1[v] = dvv * p;
        }
    }
}

// ---------------- aggregation, 1 feature (layer 5) ----------------
__global__ void k_agg1f(const float* __restrict__ hw, const int* __restrict__ rowoff,
                        const int* __restrict__ colidx, const float* __restrict__ dinv,
                        const float* __restrict__ b5, int N, float* __restrict__ vvec) {
    int v = blockIdx.x * blockDim.x + threadIdx.x;
    if (v >= N) return;
    int beg = rowoff[v], end = rowoff[v + 1];
    float s = 0.f;
    for (int i = beg; i < end; ++i) s += hw[colidx[i]];
    float h = dinv[v] * s + b5[0];
    vvec[v] = h >= 0.f ? h : 0.01f * h;
}

// ---------------- fc1 partial ----------------
__global__ __launch_bounds__(128) void k_fc1(const float* __restrict__ vvec, const float* __restrict__ fc1W,
                                             int N, float* __restrict__ accum) {
    int o = threadIdx.x;
    int rpb = (N + gridDim.x - 1) / gridDim.x;
    int r0 = blockIdx.x * rpb;
    int r1 = r0 + rpb;
    if (r1 > N) r1 = N;
    float acc = 0.f;
    for (int r = r0; r < r1; ++r) acc += vvec[r] * fc1W[(size_t)r * 128 + o];
    atomicAdd(&accum[o], acc);
}

// ---------------- fc2 final ----------------
__global__ __launch_bounds__(128) void k_fc2(const float* __restrict__ accum, const float* __restrict__ fc1b,
                                             const float* __restrict__ fc2W, const float* __restrict__ fc2b,
                                             float* __restrict__ outp) {
    __shared__ float s1[128];
    int t = threadIdx.x;
    float h = accum[t] + fc1b[t];
    s1[t] = h > 0.f ? h : 0.f;
    __syncthreads();
    float acc = fc2b[t];
    for (int o = 0; o < 128; ++o) acc += s1[o] * fc2W[o * 128 + t];
    outp[t] = acc > 0.f ? acc : 0.f;
}

extern "C" void kernel_launch(void* const* d_in, const int* in_sizes, int n_in,
                              void* d_out, int out_size, void* d_ws, size_t ws_size,
                              hipStream_t stream) {
    const float* x = (const float*)d_in[0];
    const int* ei = (const int*)d_in[2];
    const float* emb = (const float*)d_in[3];
    const float* W1 = (const float*)d_in[4];
    const float* b1 = (const float*)d_in[5];
    const float* W2 = (const float*)d_in[6];
    const float* b2 = (const float*)d_in[7];
    const float* W3 = (const float*)d_in[8];
    const float* b3 = (const float*)d_in[9];
    const float* W4 = (const float*)d_in[10];
    const float* b4 = (const float*)d_in[11];
    const float* W5 = (const float*)d_in[12];
    const float* b5 = (const float*)d_in[13];
    const float* fc1W = (const float*)d_in[14];
    const float* fc1b = (const float*)d_in[15];
    const float* fc2W = (const float*)d_in[16];
    const float* fc2b = (const float*)d_in[17];

    int N = in_sizes[0] / FEATN;
    int E = in_sizes[2] / 2;
    int NNZ = E + N;
    int NBC = (N + CSZ - 1) / CSZ;

    char* w = (char*)d_ws;
    auto alloc = [&](size_t bytes) {
        char* p = w;
        w += (bytes + 255) & ~(size_t)255;
        return p;
    };
    float* dinv   = (float*)alloc((size_t)N * 4);
    int*   rowoff = (int*)alloc((size_t)(N + 1) * 4);
    int*   colidx = (int*)alloc((size_t)NNZ * 4);
    float* valv   = (float*)alloc((size_t)N * 4);
    float* accum  = (float*)alloc(512);
    int*   flag   = (int*)alloc(256);
    int*   gtails = (int*)alloc((size_t)NBC * 4);
    int*   boff   = (int*)alloc((size_t)NBC * 4);
    unsigned int* bb = (unsigned int*)alloc((size_t)NBC * CAP2 * 4);
    unsigned short* Wf = (unsigned short*)alloc((size_t)KT_ALL * 4 * 64 * 8 * 2);
    unsigned short* g1 = (unsigned short*)alloc((size_t)N * 64 * 2);
    unsigned short* g2 = (unsigned short*)alloc((size_t)N * 32 * 2);
    unsigned short* g3 = (unsigned short*)alloc((size_t)N * 32 * 2);
    float* g5     = (float*)alloc((size_t)N * 4);
    float* vvec   = (float*)alloc((size_t)N * 4);

    int nb = (N + 255) / 256;

    k_detect<<<1, 256, 0, stream>>>(ei, flag, gtails, NBC, accum);
    k_p1<<<(E + EPB - 1) / EPB, 256, 0, stream>>>(ei, E, N, NBC, flag, gtails, bb);
    k_p1b<<<1, 256, 0, stream>>>(gtails, N, NBC, boff, rowoff + N);
    k_p2<<<NBC, 256, 0, stream>>>(bb, gtails, boff, N, rowoff, dinv, colidx);
    k_val<<<nb, 256, 0, stream>>>(x, emb, N, valv);
    k_prepW<<<(KT_ALL * 4 * 64 * 8 + 255) / 256, 256, 0, stream>>>(W1, Wf);

    k_gemm1m<<<(N + 63) / 64, 256, 0, stream>>>(x, Wf, W1, valv, dinv, N, g1);

    // layer1 agg + W2 ; layer2 agg + W3 ; layer3 agg(+res) + W4 ; layer4 agg(+res) + W5
    k_fagg<64, 32, 0><<<(N + 3) / 4, 256, 0, stream>>>(g1, rowoff, colidx, dinv, b1, W2, N, g2, nullptr);
    k_fagg<32, 32, 0><<<(N + 7) / 8, 256, 0, stream>>>(g2, rowoff, colidx, dinv, b2, W3, N, g3, nullptr);
    k_fagg<32, 32, 1><<<(N + 7) / 8, 256, 0, stream>>>(g3, rowoff, colidx, dinv, b3, W4, N, g2, nullptr);
    k_fagg<32, 1, 1><<<(N + 7) / 8, 256, 0, stream>>>(g2, rowoff, colidx, dinv, b4, W5, N, nullptr, g5);

    k_agg1f<<<nb, 256, 0, stream>>>(g5, rowoff, colidx, dinv, b5, N, vvec);

    k_fc1<<<300, 128, 0, stream>>>(vvec, fc1W, N, accum);
    k_fc2<<<1, 128, 0, stream>>>(accum, fc1b, fc2W, fc2b, (float*)d_out);
}

// Round 11
// 249.614 us; speedup vs baseline: 1.3002x; 1.0657x over previous
//
#include <hip/hip_runtime.h>
#include <hip/hip_bf16.h>

#define FEATN 898
#define EMBD 128
#define KT_FULL 28          // 28 full k-tiles of 32 (896); tile 28 (k=896..897) on register path
#define KT_ALL 29           // padded tiles in Wfrag
#define CH 4                // k-tiles per async-staged chunk
#define CBITS 8
#define CSZ 256             // nodes per coarse bucket
#define CAP2 12288          // per-bucket capacity (mean ~8183, +45 sigma)
#define EPB 4096            // edges per p1 block

typedef __bf16 bf16x8 __attribute__((ext_vector_type(8)));
typedef float f32x4 __attribute__((ext_vector_type(4)));
typedef unsigned short ushort8 __attribute__((ext_vector_type(8)));

__device__ inline unsigned short f2bf(float f) {
    unsigned int u = __float_as_uint(f);
    unsigned int r = u + 0x7fffu + ((u >> 16) & 1u);   // RNE
    return (unsigned short)(r >> 16);
}
__device__ inline float bfh(unsigned short u) {
    return __uint_as_float((unsigned int)u << 16);
}
__device__ inline unsigned int pk_bf2(float a, float b) {
    __hip_bfloat162 h = __float22bfloat162_rn(make_float2(a, b));
    unsigned int r;
    __builtin_memcpy(&r, &h, 4);
    return r;
}
// async global->LDS DMA, 16B/lane: dest = lds base (wave-uniform) + lane*16; src per-lane
__device__ inline void gl16(const void* g, void* l) {
    __builtin_amdgcn_global_load_lds((const __attribute__((address_space(1))) unsigned int*)g,
                                     (__attribute__((address_space(3))) unsigned int*)l,
                                     16, 0, 0);
}

// ---------------- detect layout + zero gtails/accum (fused init) ----------------
__global__ void k_detect(const int* __restrict__ ei32, int* __restrict__ flag,
                         int* __restrict__ gtails, int nbc, float* __restrict__ accum) {
    __shared__ int any;
    int t = threadIdx.x;
    if (t == 0) any = 0;
    __syncthreads();
    if (ei32[2 * t + 1] != 0) atomicOr(&any, 1);
    for (int i = t; i < nbc; i += 256) gtails[i] = 0;
    if (t < 128) accum[t] = 0.f;
    __syncthreads();
    if (t == 0) flag[0] = any;   // 1 = int32 layout, 0 = int64 layout
}

// ---------------- p1: counting-sort pass ----------------
__global__ __launch_bounds__(256) void k_p1(const int* __restrict__ ei, int E, int N, int nbc,
                                            const int* __restrict__ flag,
                                            int* __restrict__ gtails, unsigned int* __restrict__ bb) {
    __shared__ int hist[256], curs[256];
    int t = threadIdx.x;
    hist[t] = 0;
    __syncthreads();
    int e0 = blockIdx.x * EPB;
    int f = flag[0];
#pragma unroll
    for (int i = 0; i < EPB / 256; ++i) {
        int e = e0 + i * 256 + t;
        if (e < E) {
            int d = f ? ei[(size_t)E + e] : ei[2 * ((size_t)E + e)];
            d = min(max(d, 0), N - 1);
            atomicAdd(&hist[d >> CBITS], 1);
        }
    }
    __syncthreads();
    if (t < nbc) curs[t] = (hist[t] > 0) ? atomicAdd(&gtails[t], hist[t]) : 0;
    __syncthreads();
#pragma unroll
    for (int i = 0; i < EPB / 256; ++i) {
        int e = e0 + i * 256 + t;
        if (e < E) {
            int s = f ? ei[e] : ei[2 * (size_t)e];
            int d = f ? ei[(size_t)E + e] : ei[2 * ((size_t)E + e)];
            s = min(max(s, 0), N - 1);
            d = min(max(d, 0), N - 1);
            int c = d >> CBITS;
            int pos = atomicAdd(&curs[c], 1);
            if (pos < CAP2) bb[(size_t)c * CAP2 + pos] = ((unsigned)s << CBITS) | (unsigned)(d & (CSZ - 1));
        }
    }
}

// ---------------- p1b: exclusive scan of bucket totals (incl. self loops) ----------------
__global__ void k_p1b(const int* __restrict__ gtails, int N, int nbc,
                      int* __restrict__ boff, int* __restrict__ rowoffN) {
    __shared__ int s[256];
    int t = threadIdx.x;
    int tot = 0;
    if (t < nbc) tot = min(gtails[t], CAP2) + min(CSZ, N - t * CSZ);
    s[t] = tot;
    __syncthreads();
    for (int o = 1; o < 256; o <<= 1) {
        int v = (t >= o) ? s[t - o] : 0;
        __syncthreads();
        s[t] += v;
        __syncthreads();
    }
    if (t < nbc) boff[t] = s[t] - tot;
    if (t == 255) rowoffN[0] = s[255];
}

// ---------------- p2: per-bucket CSR build in LDS ----------------
__global__ __launch_bounds__(256) void k_p2(const unsigned int* __restrict__ bb,
                                            const int* __restrict__ gtails, const int* __restrict__ boff,
                                            int N, int* __restrict__ rowoff, float* __restrict__ dinv,
                                            int* __restrict__ colidx) {
    __shared__ unsigned int stash[CAP2];     // 48 KB
    __shared__ int hist[CSZ], curs[CSZ], sc[CSZ];
    int b = blockIdx.x;
    int t = threadIdx.x;
    int node0 = b * CSZ;
    int nbn = min(CSZ, N - node0);
    int T = min(gtails[b], CAP2);
    hist[t] = 0;
    __syncthreads();
    for (int i = t; i < T; i += 256) {
        unsigned int u = bb[(size_t)b * CAP2 + i];
        stash[i] = u;
        atomicAdd(&hist[u & (CSZ - 1)], 1);
    }
    __syncthreads();
    int v = (t < nbn) ? hist[t] + 1 : 0;
    sc[t] = v;
    __syncthreads();
    for (int o = 1; o < 256; o <<= 1) {
        int x_ = (t >= o) ? sc[t - o] : 0;
        __syncthreads();
        sc[t] += x_;
        __syncthreads();
    }
    int base = boff[b];
    if (t < nbn) {
        int node = node0 + t;
        int ex = sc[t] - v;
        rowoff[node] = base + ex;
        dinv[node] = rsqrtf((float)(hist[t] + 1));
        colidx[base + ex] = node;            // self loop first
        curs[t] = ex + 1;
    }
    __syncthreads();
    for (int i = t; i < T; i += 256) {
        unsigned int u = stash[i];
        int slot = atomicAdd(&curs[u & (CSZ - 1)], 1);
        colidx[base + slot] = (int)(u >> CBITS);
    }
}

// ---------------- injected scalar: feat[i][0] = emb[poi[i>>7]][i&127] ----------------
__global__ void k_val(const float* __restrict__ x, const float* __restrict__ emb,
                      int N, float* __restrict__ valv) {
    int i = blockIdx.x * blockDim.x + threadIdx.x;
    if (i < N) {
        int r = i >> 7;
        int poi = (int)x[(size_t)r * FEATN];
        poi = min(max(poi, 0), N - 1);
        valv[i] = emb[(size_t)poi * EMBD + (i & 127)];
    }
}

// ---------------- Wfrag prep ----------------
__global__ void k_prepW(const float* __restrict__ W1, unsigned short* __restrict__ Wf) {
    int id = blockIdx.x * 256 + threadIdx.x;
    if (id >= KT_ALL * 4 * 64 * 8) return;
    int e = id & 7;
    int l = (id >> 3) & 63;
    int nt = (id >> 9) & 3;
    int kt = id >> 11;
    int k = kt * 32 + (l >> 4) * 8 + e;
    int n = nt * 16 + (l & 15);
    float v = (k < FEATN) ? W1[(size_t)k * 64 + n] : 0.f;
    Wf[id] = f2bf(v);
}

// ---------------- GEMM1 via MFMA: async global_load_lds staging, fragment-order f32 x ----------------
// 32 rows / 128 threads (2 waves). x staged as f32 in A-frag order (per-lane global gather,
// linear LDS dest); converted with cvt_pk in the inner loop. Wf staged linearly. All inner
// ds_reads lane-contiguous (conflict-free). Tail k-tile + Wf tail on register path.
__global__ __launch_bounds__(128) void k_gemm1m(const float* __restrict__ x,
                                                const unsigned short* __restrict__ Wf,
                                                const float* __restrict__ W1,
                                                const float* __restrict__ valv,
                                                const float* __restrict__ dinv, int N,
                                                unsigned short* __restrict__ out) {
    __shared__ float xf[2][CH][2][256];     // 16 KB: [wave][kt][h][lane*4 f32]
    __shared__ ushort8 wlds[CH * 4 * 64];   // 16 KB: [ (kt*4+nt)*64 + lane ]
    int t = threadIdx.x;
    int w = t >> 6;
    int l = t & 63;
    int r0 = blockIdx.x * 32;
    int rA = r0 + w * 16 + (l & 15);
    int rC = (rA < N) ? rA : (N - 1);       // clamp loads; stores guarded in epilogue
    int kg = l >> 4;
    const float* xrow = x + (size_t)rC * FEATN;
    const ushort8* wfg = (const ushort8*)Wf;

    f32x4 acc[4];
#pragma unroll
    for (int nt = 0; nt < 4; ++nt) acc[nt] = (f32x4){0.f, 0.f, 0.f, 0.f};

    for (int c0 = 0; c0 < KT_FULL; c0 += CH) {   // 7 chunks of 4 k-tiles
        __syncthreads();                          // prior chunk's ds_reads complete
        // async x: 8 DMA per wave; lane l gathers its fragment granule (row rC, kg, h)
#pragma unroll
        for (int kt = 0; kt < CH; ++kt)
#pragma unroll
            for (int h = 0; h < 2; ++h)
                gl16(xrow + (c0 + kt) * 32 + kg * 8 + h * 4, &xf[w][kt][h][0]);
        // async Wf: 8 DMA per wave, linear
#pragma unroll
        for (int q = 0; q < 8; ++q) {
            int blkg = w * 8 + q;                 // 0..15 granule-blocks of this chunk
            gl16(&wfg[(size_t)c0 * 256 + blkg * 64 + l], &wlds[blkg * 64]);
        }
        __syncthreads();                          // vmcnt(0) drain inserted by compiler
#pragma unroll
        for (int kt = 0; kt < CH; ++kt) {
            f32x4 lo = *(const f32x4*)&xf[w][kt][0][l * 4];
            f32x4 hi = *(const f32x4*)&xf[w][kt][1][l * 4];
            if (c0 == 0 && kt == 0 && kg == 0) lo.x = 0.f;   // zero POI-id col; corr in epilogue
            ushort8 u;
            unsigned int p0 = pk_bf2(lo.x, lo.y), p1 = pk_bf2(lo.z, lo.w);
            unsigned int p2 = pk_bf2(hi.x, hi.y), p3 = pk_bf2(hi.z, hi.w);
            u[0] = (unsigned short)p0; u[1] = (unsigned short)(p0 >> 16);
            u[2] = (unsigned short)p1; u[3] = (unsigned short)(p1 >> 16);
            u[4] = (unsigned short)p2; u[5] = (unsigned short)(p2 >> 16);
            u[6] = (unsigned short)p3; u[7] = (unsigned short)(p3 >> 16);
            bf16x8 a;
            __builtin_memcpy(&a, &u, 16);
#pragma unroll
            for (int nt = 0; nt < 4; ++nt) {
                bf16x8 b;
                ushort8 ub = wlds[(kt * 4 + nt) * 64 + l];   // lane-contiguous ds_read_b128
                __builtin_memcpy(&b, &ub, 16);
                acc[nt] = __builtin_amdgcn_mfma_f32_16x16x32_bf16(a, b, acc[nt], 0, 0, 0);
            }
        }
    }
    // tail k-tile (k=896..897): register path, Wf tail from global (L2-hot)
    {
        ushort8 u = (ushort8)0;
        if (kg == 0) {
            float2 q = *(const float2*)(xrow + 896);
            u[0] = f2bf(q.x);
            u[1] = f2bf(q.y);
        }
        bf16x8 a;
        __builtin_memcpy(&a, &u, 16);
#pragma unroll
        for (int nt = 0; nt < 4; ++nt) {
            bf16x8 b;
            ushort8 ub = wfg[(KT_FULL * 4 + nt) * 64 + l];
            __builtin_memcpy(&b, &ub, 16);
            acc[nt] = __builtin_amdgcn_mfma_f32_16x16x32_bf16(a, b, acc[nt], 0, 0, 0);
        }
    }

    // epilogue: C/D layout col=lane&15, row=(lane>>4)*4+reg
    int colb = l & 15;
    int rquad = l >> 4;
    int rowbase = r0 + w * 16 + rquad * 4;
    float dv[4], vv[4];
#pragma unroll
    for (int rg = 0; rg < 4; ++rg) {
        int row = rowbase + rg;
        int rc = (row < N) ? row : (N - 1);
        dv[rg] = dinv[rc];
        vv[rg] = valv[rc];
    }
#pragma unroll
    for (int nt = 0; nt < 4; ++nt) {
        int col = nt * 16 + colb;
        float wcol = W1[col];
#pragma unroll
        for (int rg = 0; rg < 4; ++rg) {
            int row = rowbase + rg;
            if (row < N)
                out[(size_t)row * 64 + col] = f2bf(dv[rg] * (acc[nt][rg] + vv[rg] * wcol));
        }
    }
}

// ---------------- fused aggregation + next-layer GEMM (8 gathers in flight) ----------------
template <int IN, int ON, int EPI>
__global__ __launch_bounds__(256) void k_fagg(const unsigned short* __restrict__ gin,
                                              const int* __restrict__ rowoff,
                                              const int* __restrict__ colidx,
                                              const float* __restrict__ dinv,
                                              const float* __restrict__ bias,
                                              const float* __restrict__ W, int N,
                                              unsigned short* __restrict__ gout,
                                              float* __restrict__ gout1) {
    constexpr int NPB = 256 / IN;
    __shared__ float ws[IN * ON];
    __shared__ float hb[NPB][IN + 1];
    for (int j = threadIdx.x; j < IN * ON; j += 256) ws[j] = W[j];
    __syncthreads();
    int slot = threadIdx.x / IN;
    int lane = threadIdx.x % IN;
    int v = blockIdx.x * NPB + slot;
    bool act = v < N;
    float dvv = 0.f;
    if (act) {
        int beg = rowoff[v], end = rowoff[v + 1];
        dvv = dinv[v];
        float a0 = 0.f, a1 = 0.f, a2 = 0.f, a3 = 0.f;
        int i = beg;
        for (; i + 8 <= end; i += 8) {
            int u0 = colidx[i],     u1 = colidx[i + 1], u2 = colidx[i + 2], u3 = colidx[i + 3];
            int u4 = colidx[i + 4], u5 = colidx[i + 5], u6 = colidx[i + 6], u7 = colidx[i + 7];
            float b0 = bfh(gin[(size_t)u0 * IN + lane]);
            float b1 = bfh(gin[(size_t)u1 * IN + lane]);
            float b2 = bfh(gin[(size_t)u2 * IN + lane]);
            float b3 = bfh(gin[(size_t)u3 * IN + lane]);
            float b4 = bfh(gin[(size_t)u4 * IN + lane]);
            float b5 = bfh(gin[(size_t)u5 * IN + lane]);
            float b6 = bfh(gin[(size_t)u6 * IN + lane]);
            float b7 = bfh(gin[(size_t)u7 * IN + lane]);
            a0 += b0 + b4; a1 += b1 + b5; a2 += b2 + b6; a3 += b3 + b7;
        }
        for (; i < end; ++i) a0 += bfh(gin[(size_t)colidx[i] * IN + lane]);
        float t_ = dvv * ((a0 + a1) + (a2 + a3)) + bias[lane];
        float h = (EPI == 0) ? (t_ >= 0.f ? t_ : 0.01f * t_) : (t_ >= 0.f ? 2.f * t_ : 1.01f * t_);
        hb[slot][lane] = h;                       // same-wave LDS; hw-ordered
    }
    if (act) {
        if (ON == 32) {
            int c = lane & 31;
            float acc = 0.f;
            if (IN == 64) {
                int k0 = (lane >> 5) * 32;
#pragma unroll
                for (int k = 0; k < 32; ++k) acc += hb[slot][k0 + k] * ws[(k0 + k) * 32 + c];
                acc += __shfl_xor(acc, 32, 64);   // combine the two k-halves
                if (lane < 32) gout[(size_t)v * 32 + c] = f2bf(dvv * acc);
            } else {
#pragma unroll
                for (int k = 0; k < 32; ++k) acc += hb[slot][k] * ws[k * 32 + c];
                gout[(size_t)v * 32 + c] = f2bf(dvv * acc);
            }
        } else {                                   // ON==1, IN==32
            float p = hb[slot][lane] * ws[lane];
#pragma unroll
            for (int o = 16; o > 0; o >>= 1) p += __shfl_down(p, o, 32);
            if (lane == 0) gout1[v] = dvv * p;
        }
    }
}

// ---------------- aggregation, 1 feature (layer 5) ----------------
__global__ void k_agg1f(const float* __restrict__ hw, const int* __restrict__ rowoff,
                        const int* __restrict__ colidx, const float* __restrict__ dinv,
                        const float* __restrict__ b5, int N, float* __restrict__ vvec) {
    int v = blockIdx.x * blockDim.x + threadIdx.x;
    if (v >= N) return;
    int beg = rowoff[v], end = rowoff[v + 1];
    float s = 0.f;
    for (int i = beg; i < end; ++i) s += hw[colidx[i]];
    float h = dinv[v] * s + b5[0];
    vvec[v] = h >= 0.f ? h : 0.01f * h;
}

// ---------------- fc1 partial ----------------
__global__ __launch_bounds__(128) void k_fc1(const float* __restrict__ vvec, const float* __restrict__ fc1W,
                                             int N, float* __restrict__ accum) {
    int o = threadIdx.x;
    int rpb = (N + gridDim.x - 1) / gridDim.x;
    int r0 = blockIdx.x * rpb;
    int r1 = r0 + rpb;
    if (r1 > N) r1 = N;
    float acc = 0.f;
    for (int r = r0; r < r1; ++r) acc += vvec[r] * fc1W[(size_t)r * 128 + o];
    atomicAdd(&accum[o], acc);
}

// ---------------- fc2 final ----------------
__global__ __launch_bounds__(128) void k_fc2(const float* __restrict__ accum, const float* __restrict__ fc1b,
                                             const float* __restrict__ fc2W, const float* __restrict__ fc2b,
                                             float* __restrict__ outp) {
    __shared__ float s1[128];
    int t = threadIdx.x;
    float h = accum[t] + fc1b[t];
    s1[t] = h > 0.f ? h : 0.f;
    __syncthreads();
    float acc = fc2b[t];
    for (int o = 0; o < 128; ++o) acc += s1[o] * fc2W[o * 128 + t];
    outp[t] = acc > 0.f ? acc : 0.f;
}

extern "C" void kernel_launch(void* const* d_in, const int* in_sizes, int n_in,
                              void* d_out, int out_size, void* d_ws, size_t ws_size,
                              hipStream_t stream) {
    const float* x = (const float*)d_in[0];
    const int* ei = (const int*)d_in[2];
    const float* emb = (const float*)d_in[3];
    const float* W1 = (const float*)d_in[4];
    const float* b1 = (const float*)d_in[5];
    const float* W2 = (const float*)d_in[6];
    const float* b2 = (const float*)d_in[7];
    const float* W3 = (const float*)d_in[8];
    const float* b3 = (const float*)d_in[9];
    const float* W4 = (const float*)d_in[10];
    const float* b4 = (const float*)d_in[11];
    const float* W5 = (const float*)d_in[12];
    const float* b5 = (const float*)d_in[13];
    const float* fc1W = (const float*)d_in[14];
    const float* fc1b = (const float*)d_in[15];
    const float* fc2W = (const float*)d_in[16];
    const float* fc2b = (const float*)d_in[17];

    int N = in_sizes[0] / FEATN;
    int E = in_sizes[2] / 2;
    int NNZ = E + N;
    int NBC = (N + CSZ - 1) / CSZ;

    char* w = (char*)d_ws;
    auto alloc = [&](size_t bytes) {
        char* p = w;
        w += (bytes + 255) & ~(size_t)255;
        return p;
    };
    float* dinv   = (float*)alloc((size_t)N * 4);
    int*   rowoff = (int*)alloc((size_t)(N + 1) * 4);
    int*   colidx = (int*)alloc((size_t)NNZ * 4);
    float* valv   = (float*)alloc((size_t)N * 4);
    float* accum  = (float*)alloc(512);
    int*   flag   = (int*)alloc(256);
    int*   gtails = (int*)alloc((size_t)NBC * 4);
    int*   boff   = (int*)alloc((size_t)NBC * 4);
    unsigned int* bb = (unsigned int*)alloc((size_t)NBC * CAP2 * 4);
    unsigned short* Wf = (unsigned short*)alloc((size_t)KT_ALL * 4 * 64 * 8 * 2);
    unsigned short* g1 = (unsigned short*)alloc((size_t)N * 64 * 2);
    unsigned short* g2 = (unsigned short*)alloc((size_t)N * 32 * 2);
    unsigned short* g3 = (unsigned short*)alloc((size_t)N * 32 * 2);
    float* g5     = (float*)alloc((size_t)N * 4);
    float* vvec   = (float*)alloc((size_t)N * 4);

    int nb = (N + 255) / 256;

    k_detect<<<1, 256, 0, stream>>>(ei, flag, gtails, NBC, accum);
    k_p1<<<(E + EPB - 1) / EPB, 256, 0, stream>>>(ei, E, N, NBC, flag, gtails, bb);
    k_p1b<<<1, 256, 0, stream>>>(gtails, N, NBC, boff, rowoff + N);
    k_p2<<<NBC, 256, 0, stream>>>(bb, gtails, boff, N, rowoff, dinv, colidx);
    k_val<<<nb, 256, 0, stream>>>(x, emb, N, valv);
    k_prepW<<<(KT_ALL * 4 * 64 * 8 + 255) / 256, 256, 0, stream>>>(W1, Wf);

    k_gemm1m<<<(N + 31) / 32, 128, 0, stream>>>(x, Wf, W1, valv, dinv, N, g1);

    // layer1 agg + W2 ; layer2 agg + W3 ; layer3 agg(+res) + W4 ; layer4 agg(+res) + W5
    k_fagg<64, 32, 0><<<(N + 3) / 4, 256, 0, stream>>>(g1, rowoff, colidx, dinv, b1, W2, N, g2, nullptr);
    k_fagg<32, 32, 0><<<(N + 7) / 8, 256, 0, stream>>>(g2, rowoff, colidx, dinv, b2, W3, N, g3, nullptr);
    k_fagg<32, 32, 1><<<(N + 7) / 8, 256, 0, stream>>>(g3, rowoff, colidx, dinv, b3, W4, N, g2, nullptr);
    k_fagg<32, 1, 1><<<(N + 7) / 8, 256, 0, stream>>>(g2, rowoff, colidx, dinv, b4, W5, N, nullptr, g5);

    k_agg1f<<<nb, 256, 0, stream>>>(g5, rowoff, colidx, dinv, b5, N, vvec);

    k_fc1<<<300, 128, 0, stream>>>(vvec, fc1W, N, accum);
    k_fc2<<<1, 128, 0, stream>>>(accum, fc1b, fc2W, fc2b, (float*)d_out);
}

// Round 12
// 224.821 us; speedup vs baseline: 1.4435x; 1.1103x over previous
//
#include <hip/hip_runtime.h>
#include <hip/hip_bf16.h>

#define FEATN 898
#define EMBD 128
#define KT_FULL 28          // 28 full k-tiles of 32 (896); tile 28 (k=896..897) on register path
#define KT_ALL 29           // padded tiles in Wfrag
#define CH 4                // k-tiles per async-staged chunk
#define CBITS 8
#define CSZ 256             // nodes per coarse bucket
#define CAP2 12288          // per-bucket capacity (mean ~8183, +45 sigma)
#define EPB 4096            // edges per p1 block

typedef __bf16 bf16x8 __attribute__((ext_vector_type(8)));
typedef float f32x4 __attribute__((ext_vector_type(4)));
typedef unsigned short ushort8 __attribute__((ext_vector_type(8)));

__device__ inline unsigned short f2bf(float f) {
    unsigned int u = __float_as_uint(f);
    unsigned int r = u + 0x7fffu + ((u >> 16) & 1u);   // RNE
    return (unsigned short)(r >> 16);
}
__device__ inline float bfh(unsigned short u) {
    return __uint_as_float((unsigned int)u << 16);
}
__device__ inline float bflo(unsigned int u) {
    return __uint_as_float(u << 16);
}
__device__ inline float bfhi(unsigned int u) {
    return __uint_as_float(u & 0xFFFF0000u);
}
__device__ inline unsigned int pk_bf2(float a, float b) {
    __hip_bfloat162 h = __float22bfloat162_rn(make_float2(a, b));
    unsigned int r;
    __builtin_memcpy(&r, &h, 4);
    return r;
}
// async global->LDS DMA, 16B/lane: dest = lds base (wave-uniform) + lane*16; src per-lane
__device__ inline void gl16(const void* g, void* l) {
    __builtin_amdgcn_global_load_lds((const __attribute__((address_space(1))) unsigned int*)g,
                                     (__attribute__((address_space(3))) unsigned int*)l,
                                     16, 0, 0);
}

// ---------------- detect layout + zero gtails/accum (fused init) ----------------
__global__ void k_detect(const int* __restrict__ ei32, int* __restrict__ flag,
                         int* __restrict__ gtails, int nbc, float* __restrict__ accum) {
    __shared__ int any;
    int t = threadIdx.x;
    if (t == 0) any = 0;
    __syncthreads();
    if (ei32[2 * t + 1] != 0) atomicOr(&any, 1);
    for (int i = t; i < nbc; i += 256) gtails[i] = 0;
    if (t < 128) accum[t] = 0.f;
    __syncthreads();
    if (t == 0) flag[0] = any;   // 1 = int32 layout, 0 = int64 layout
}

// ---------------- p1 v3: in-LDS counting sort per block -> coalesced global runs ----------------
__global__ __launch_bounds__(256) void k_p1(const int* __restrict__ ei, int E, int N, int nbc,
                                            const int* __restrict__ flag,
                                            int* __restrict__ gtails, unsigned int* __restrict__ bb) {
    __shared__ unsigned int stash[EPB];       // 16 KB, sorted by bucket
    __shared__ int hist[256], loff[256], gbase[256], lcur[256], sc[256];
    int t = threadIdx.x;
    hist[t] = 0;
    __syncthreads();
    int e0 = blockIdx.x * EPB;
    int f = flag[0];
    // pass A: histogram
#pragma unroll
    for (int i = 0; i < EPB / 256; ++i) {
        int e = e0 + i * 256 + t;
        if (e < E) {
            int d = f ? ei[(size_t)E + e] : ei[2 * ((size_t)E + e)];
            d = min(max(d, 0), N - 1);
            atomicAdd(&hist[d >> CBITS], 1);
        }
    }
    __syncthreads();
    // inclusive scan of hist -> exclusive loff
    int v = hist[t];
    sc[t] = v;
    __syncthreads();
    for (int o = 1; o < 256; o <<= 1) {
        int x_ = (t >= o) ? sc[t - o] : 0;
        __syncthreads();
        sc[t] += x_;
        __syncthreads();
    }
    loff[t] = sc[t] - v;
    lcur[t] = sc[t] - v;
    // reserve global runs (hist[t]>0 implies t<nbc)
    gbase[t] = (v > 0) ? atomicAdd(&gtails[t], v) : 0;
    __syncthreads();
    // pass B: scatter into LDS stash sorted by bucket; pack (src<<16)|dst (both <2^16)
#pragma unroll
    for (int i = 0; i < EPB / 256; ++i) {
        int e = e0 + i * 256 + t;
        if (e < E) {
            int s_ = f ? ei[e] : ei[2 * (size_t)e];
            int d = f ? ei[(size_t)E + e] : ei[2 * ((size_t)E + e)];
            s_ = min(max(s_, 0), N - 1);
            d = min(max(d, 0), N - 1);
            int p = atomicAdd(&lcur[d >> CBITS], 1);
            stash[p] = ((unsigned)s_ << 16) | (unsigned)d;
        }
    }
    __syncthreads();
    // pass C: coalesced write of sorted entries to this block's reserved runs
    int T = min(EPB, E - e0);
    for (int i = t; i < T; i += 256) {
        unsigned int u = stash[i];
        int d = (int)(u & 0xFFFFu);
        int c = d >> CBITS;
        int pos = gbase[c] + (i - loff[c]);
        if (pos < CAP2)
            bb[(size_t)c * CAP2 + pos] = ((u >> 16) << CBITS) | (unsigned)(d & (CSZ - 1));
    }
}

// ---------------- p1b: exclusive scan of bucket totals (incl. self loops) ----------------
__global__ void k_p1b(const int* __restrict__ gtails, int N, int nbc,
                      int* __restrict__ boff, int* __restrict__ rowoffN) {
    __shared__ int s[256];
    int t = threadIdx.x;
    int tot = 0;
    if (t < nbc) tot = min(gtails[t], CAP2) + min(CSZ, N - t * CSZ);
    s[t] = tot;
    __syncthreads();
    for (int o = 1; o < 256; o <<= 1) {
        int v = (t >= o) ? s[t - o] : 0;
        __syncthreads();
        s[t] += v;
        __syncthreads();
    }
    if (t < nbc) boff[t] = s[t] - tot;
    if (t == 255) rowoffN[0] = s[255];
}

// ---------------- p2: per-bucket CSR build in LDS ----------------
__global__ __launch_bounds__(256) void k_p2(const unsigned int* __restrict__ bb,
                                            const int* __restrict__ gtails, const int* __restrict__ boff,
                                            int N, int* __restrict__ rowoff, float* __restrict__ dinv,
                                            int* __restrict__ colidx) {
    __shared__ unsigned int stash[CAP2];     // 48 KB
    __shared__ int hist[CSZ], curs[CSZ], sc[CSZ];
    int b = blockIdx.x;
    int t = threadIdx.x;
    int node0 = b * CSZ;
    int nbn = min(CSZ, N - node0);
    int T = min(gtails[b], CAP2);
    hist[t] = 0;
    __syncthreads();
    for (int i = t; i < T; i += 256) {
        unsigned int u = bb[(size_t)b * CAP2 + i];
        stash[i] = u;
        atomicAdd(&hist[u & (CSZ - 1)], 1);
    }
    __syncthreads();
    int v = (t < nbn) ? hist[t] + 1 : 0;
    sc[t] = v;
    __syncthreads();
    for (int o = 1; o < 256; o <<= 1) {
        int x_ = (t >= o) ? sc[t - o] : 0;
        __syncthreads();
        sc[t] += x_;
        __syncthreads();
    }
    int base = boff[b];
    if (t < nbn) {
        int node = node0 + t;
        int ex = sc[t] - v;
        rowoff[node] = base + ex;
        dinv[node] = rsqrtf((float)(hist[t] + 1));
        colidx[base + ex] = node;            // self loop first
        curs[t] = ex + 1;
    }
    __syncthreads();
    for (int i = t; i < T; i += 256) {
        unsigned int u = stash[i];
        int slot = atomicAdd(&curs[u & (CSZ - 1)], 1);
        colidx[base + slot] = (int)(u >> CBITS);
    }
}

// ---------------- injected scalar: feat[i][0] = emb[poi[i>>7]][i&127] ----------------
__global__ void k_val(const float* __restrict__ x, const float* __restrict__ emb,
                      int N, float* __restrict__ valv) {
    int i = blockIdx.x * blockDim.x + threadIdx.x;
    if (i < N) {
        int r = i >> 7;
        int poi = (int)x[(size_t)r * FEATN];
        poi = min(max(poi, 0), N - 1);
        valv[i] = emb[(size_t)poi * EMBD + (i & 127)];
    }
}

// ---------------- Wfrag prep ----------------
__global__ void k_prepW(const float* __restrict__ W1, unsigned short* __restrict__ Wf) {
    int id = blockIdx.x * 256 + threadIdx.x;
    if (id >= KT_ALL * 4 * 64 * 8) return;
    int e = id & 7;
    int l = (id >> 3) & 63;
    int nt = (id >> 9) & 3;
    int kt = id >> 11;
    int k = kt * 32 + (l >> 4) * 8 + e;
    int n = nt * 16 + (l & 15);
    float v = (k < FEATN) ? W1[(size_t)k * 64 + n] : 0.f;
    Wf[id] = f2bf(v);
}

// ---------------- GEMM1 via MFMA: async global_load_lds staging (unchanged from R11) ----------------
__global__ __launch_bounds__(128) void k_gemm1m(const float* __restrict__ x,
                                                const unsigned short* __restrict__ Wf,
                                                const float* __restrict__ W1,
                                                const float* __restrict__ valv,
                                                const float* __restrict__ dinv, int N,
                                                unsigned short* __restrict__ out) {
    __shared__ float xf[2][CH][2][256];     // 16 KB: [wave][kt][h][lane*4 f32]
    __shared__ ushort8 wlds[CH * 4 * 64];   // 16 KB
    int t = threadIdx.x;
    int w = t >> 6;
    int l = t & 63;
    int r0 = blockIdx.x * 32;
    int rA = r0 + w * 16 + (l & 15);
    int rC = (rA < N) ? rA : (N - 1);
    int kg = l >> 4;
    const float* xrow = x + (size_t)rC * FEATN;
    const ushort8* wfg = (const ushort8*)Wf;

    f32x4 acc[4];
#pragma unroll
    for (int nt = 0; nt < 4; ++nt) acc[nt] = (f32x4){0.f, 0.f, 0.f, 0.f};

    for (int c0 = 0; c0 < KT_FULL; c0 += CH) {
        __syncthreads();
#pragma unroll
        for (int kt = 0; kt < CH; ++kt)
#pragma unroll
            for (int h = 0; h < 2; ++h)
                gl16(xrow + (c0 + kt) * 32 + kg * 8 + h * 4, &xf[w][kt][h][0]);
#pragma unroll
        for (int q = 0; q < 8; ++q) {
            int blkg = w * 8 + q;
            gl16(&wfg[(size_t)c0 * 256 + blkg * 64 + l], &wlds[blkg * 64]);
        }
        __syncthreads();
#pragma unroll
        for (int kt = 0; kt < CH; ++kt) {
            f32x4 lo = *(const f32x4*)&xf[w][kt][0][l * 4];
            f32x4 hi = *(const f32x4*)&xf[w][kt][1][l * 4];
            if (c0 == 0 && kt == 0 && kg == 0) lo.x = 0.f;   // zero POI-id col
            ushort8 u;
            unsigned int p0 = pk_bf2(lo.x, lo.y), p1 = pk_bf2(lo.z, lo.w);
            unsigned int p2 = pk_bf2(hi.x, hi.y), p3 = pk_bf2(hi.z, hi.w);
            u[0] = (unsigned short)p0; u[1] = (unsigned short)(p0 >> 16);
            u[2] = (unsigned short)p1; u[3] = (unsigned short)(p1 >> 16);
            u[4] = (unsigned short)p2; u[5] = (unsigned short)(p2 >> 16);
            u[6] = (unsigned short)p3; u[7] = (unsigned short)(p3 >> 16);
            bf16x8 a;
            __builtin_memcpy(&a, &u, 16);
#pragma unroll
            for (int nt = 0; nt < 4; ++nt) {
                bf16x8 b;
                ushort8 ub = wlds[(kt * 4 + nt) * 64 + l];
                __builtin_memcpy(&b, &ub, 16);
                acc[nt] = __builtin_amdgcn_mfma_f32_16x16x32_bf16(a, b, acc[nt], 0, 0, 0);
            }
        }
    }
    {   // tail k-tile (k=896..897)
        ushort8 u = (ushort8)0;
        if (kg == 0) {
            float2 q = *(const float2*)(xrow + 896);
            u[0] = f2bf(q.x);
            u[1] = f2bf(q.y);
        }
        bf16x8 a;
        __builtin_memcpy(&a, &u, 16);
#pragma unroll
        for (int nt = 0; nt < 4; ++nt) {
            bf16x8 b;
            ushort8 ub = wfg[(KT_FULL * 4 + nt) * 64 + l];
            __builtin_memcpy(&b, &ub, 16);
            acc[nt] = __builtin_amdgcn_mfma_f32_16x16x32_bf16(a, b, acc[nt], 0, 0, 0);
        }
    }

    int colb = l & 15;
    int rquad = l >> 4;
    int rowbase = r0 + w * 16 + rquad * 4;
    float dv[4], vv[4];
#pragma unroll
    for (int rg = 0; rg < 4; ++rg) {
        int row = rowbase + rg;
        int rc = (row < N) ? row : (N - 1);
        dv[rg] = dinv[rc];
        vv[rg] = valv[rc];
    }
#pragma unroll
    for (int nt = 0; nt < 4; ++nt) {
        int col = nt * 16 + colb;
        float wcol = W1[col];
#pragma unroll
        for (int rg = 0; rg < 4; ++rg) {
            int row = rowbase + rg;
            if (row < N)
                out[(size_t)row * 64 + col] = f2bf(dv[rg] * (acc[nt][rg] + vv[rg] * wcol));
        }
    }
}

// ---------------- fused aggregation + next-layer GEMM, bf16x2 gathers ----------------
// group = IN/2 lanes; lane g covers features (2g, 2g+1) as one uint load per neighbor.
template <int IN, int ON, int EPI>
__global__ __launch_bounds__(256) void k_fagg(const unsigned short* __restrict__ gin,
                                              const int* __restrict__ rowoff,
                                              const int* __restrict__ colidx,
                                              const float* __restrict__ dinv,
                                              const float* __restrict__ bias,
                                              const float* __restrict__ W, int N,
                                              unsigned short* __restrict__ gout,
                                              float* __restrict__ gout1) {
    constexpr int GRP = IN / 2;
    constexpr int NPB = 256 / GRP;
    __shared__ float ws[IN * ON];
    __shared__ float hb[NPB][IN + 1];
    for (int j = threadIdx.x; j < IN * ON; j += 256) ws[j] = W[j];
    __syncthreads();
    int slot = threadIdx.x / GRP;
    int g = threadIdx.x % GRP;
    int v = blockIdx.x * NPB + slot;
    if (v >= N) return;
    const unsigned int* gin2 = (const unsigned int*)gin;
    int beg = rowoff[v], end = rowoff[v + 1];
    float dvv = dinv[v];
    float alo0 = 0.f, ahi0 = 0.f, alo1 = 0.f, ahi1 = 0.f;
    float alo2 = 0.f, ahi2 = 0.f, alo3 = 0.f, ahi3 = 0.f;
    int i = beg;
    for (; i + 8 <= end; i += 8) {
        int u0 = colidx[i],     u1 = colidx[i + 1], u2 = colidx[i + 2], u3 = colidx[i + 3];
        int u4 = colidx[i + 4], u5 = colidx[i + 5], u6 = colidx[i + 6], u7 = colidx[i + 7];
        unsigned int b0 = gin2[(size_t)u0 * GRP + g];
        unsigned int b1 = gin2[(size_t)u1 * GRP + g];
        unsigned int b2 = gin2[(size_t)u2 * GRP + g];
        unsigned int b3 = gin2[(size_t)u3 * GRP + g];
        unsigned int b4 = gin2[(size_t)u4 * GRP + g];
        unsigned int b5 = gin2[(size_t)u5 * GRP + g];
        unsigned int b6 = gin2[(size_t)u6 * GRP + g];
        unsigned int b7 = gin2[(size_t)u7 * GRP + g];
        alo0 += bflo(b0) + bflo(b4); ahi0 += bfhi(b0) + bfhi(b4);
        alo1 += bflo(b1) + bflo(b5); ahi1 += bfhi(b1) + bfhi(b5);
        alo2 += bflo(b2) + bflo(b6); ahi2 += bfhi(b2) + bfhi(b6);
        alo3 += bflo(b3) + bflo(b7); ahi3 += bfhi(b3) + bfhi(b7);
    }
    for (; i < end; ++i) {
        unsigned int b0 = gin2[(size_t)colidx[i] * GRP + g];
        alo0 += bflo(b0); ahi0 += bfhi(b0);
    }
    float2 bs = ((const float2*)bias)[g];
    float tlo = dvv * ((alo0 + alo1) + (alo2 + alo3)) + bs.x;
    float thi = dvv * ((ahi0 + ahi1) + (ahi2 + ahi3)) + bs.y;
    float hlo = (EPI == 0) ? (tlo >= 0.f ? tlo : 0.01f * tlo) : (tlo >= 0.f ? 2.f * tlo : 1.01f * tlo);
    float hhi = (EPI == 0) ? (thi >= 0.f ? thi : 0.01f * thi) : (thi >= 0.f ? 2.f * thi : 1.01f * thi);
    hb[slot][2 * g] = hlo;
    hb[slot][2 * g + 1] = hhi;      // same-group (same-wave) LDS; hw-ordered
    if (ON == 32) {
        if (IN == 64) {             // GRP=32: lane g -> col g
            float acc = 0.f;
#pragma unroll
            for (int k = 0; k < 64; ++k) acc += hb[slot][k] * ws[k * 32 + g];
            gout[(size_t)v * 32 + g] = f2bf(dvv * acc);
        } else {                    // IN=32, GRP=16: lane g -> cols 2g,2g+1 (uint store)
            float a0 = 0.f, a1 = 0.f;
#pragma unroll
            for (int k = 0; k < 32; ++k) {
                float2 wv = *(const float2*)&ws[k * 32 + 2 * g];
                float h = hb[slot][k];
                a0 += h * wv.x;
                a1 += h * wv.y;
            }
            ((unsigned int*)gout)[(size_t)v * 16 + g] = pk_bf2(dvv * a0, dvv * a1);
        }
    } else {                        // ON==1, IN==32, GRP=16
        float p = hlo * ws[2 * g] + hhi * ws[2 * g + 1];
#pragma unroll
        for (int o = 8; o > 0; o >>= 1) p += __shfl_down(p, o, 16);
        if (g == 0) gout1[v] = dvv * p;
    }
}

// ---------------- aggregation, 1 feature (layer 5) ----------------
__global__ void k_agg1f(const float* __restrict__ hw, const int* __restrict__ rowoff,
                        const int* __restrict__ colidx, const float* __restrict__ dinv,
                        const float* __restrict__ b5, int N, float* __restrict__ vvec) {
    int v = blockIdx.x * blockDim.x + threadIdx.x;
    if (v >= N) return;
    int beg = rowoff[v], end = rowoff[v + 1];
    float s = 0.f;
    for (int i = beg; i < end; ++i) s += hw[colidx[i]];
    float h = dinv[v] * s + b5[0];
    vvec[v] = h >= 0.f ? h : 0.01f * h;
}

// ---------------- fc1 partial ----------------
__global__ __launch_bounds__(128) void k_fc1(const float* __restrict__ vvec, const float* __restrict__ fc1W,
                                             int N, float* __restrict__ accum) {
    int o = threadIdx.x;
    int rpb = (N + gridDim.x - 1) / gridDim.x;
    int r0 = blockIdx.x * rpb;
    int r1 = r0 + rpb;
    if (r1 > N) r1 = N;
    float acc = 0.f;
    for (int r = r0; r < r1; ++r) acc += vvec[r] * fc1W[(size_t)r * 128 + o];
    atomicAdd(&accum[o], acc);
}

// ---------------- fc2 final ----------------
__global__ __launch_bounds__(128) void k_fc2(const float* __restrict__ accum, const float* __restrict__ fc1b,
                                             const float* __restrict__ fc2W, const float* __restrict__ fc2b,
                                             float* __restrict__ outp) {
    __shared__ float s1[128];
    int t = threadIdx.x;
    float h = accum[t] + fc1b[t];
    s1[t] = h > 0.f ? h : 0.f;
    __syncthreads();
    float acc = fc2b[t];
    for (int o = 0; o < 128; ++o) acc += s1[o] * fc2W[o * 128 + t];
    outp[t] = acc > 0.f ? acc : 0.f;
}

extern "C" void kernel_launch(void* const* d_in, const int* in_sizes, int n_in,
                              void* d_out, int out_size, void* d_ws, size_t ws_size,
                              hipStream_t stream) {
    const float* x = (const float*)d_in[0];
    const int* ei = (const int*)d_in[2];
    const float* emb = (const float*)d_in[3];
    const float* W1 = (const float*)d_in[4];
    const float* b1 = (const float*)d_in[5];
    const float* W2 = (const float*)d_in[6];
    const float* b2 = (const float*)d_in[7];
    const float* W3 = (const float*)d_in[8];
    const float* b3 = (const float*)d_in[9];
    const float* W4 = (const float*)d_in[10];
    const float* b4 = (const float*)d_in[11];
    const float* W5 = (const float*)d_in[12];
    const float* b5 = (const float*)d_in[13];
    const float* fc1W = (const float*)d_in[14];
    const float* fc1b = (const float*)d_in[15];
    const float* fc2W = (const float*)d_in[16];
    const float* fc2b = (const float*)d_in[17];

    int N = in_sizes[0] / FEATN;
    int E = in_sizes[2] / 2;
    int NNZ = E + N;
    int NBC = (N + CSZ - 1) / CSZ;

    char* w = (char*)d_ws;
    auto alloc = [&](size_t bytes) {
        char* p = w;
        w += (bytes + 255) & ~(size_t)255;
        return p;
    };
    float* dinv   = (float*)alloc((size_t)N * 4);
    int*   rowoff = (int*)alloc((size_t)(N + 1) * 4);
    int*   colidx = (int*)alloc((size_t)NNZ * 4);
    float* valv   = (float*)alloc((size_t)N * 4);
    float* accum  = (float*)alloc(512);
    int*   flag   = (int*)alloc(256);
    int*   gtails = (int*)alloc((size_t)NBC * 4);
    int*   boff   = (int*)alloc((size_t)NBC * 4);
    unsigned int* bb = (unsigned int*)alloc((size_t)NBC * CAP2 * 4);
    unsigned short* Wf = (unsigned short*)alloc((size_t)KT_ALL * 4 * 64 * 8 * 2);
    unsigned short* g1 = (unsigned short*)alloc((size_t)N * 64 * 2);
    unsigned short* g2 = (unsigned short*)alloc((size_t)N * 32 * 2);
    unsigned short* g3 = (unsigned short*)alloc((size_t)N * 32 * 2);
    float* g5     = (float*)alloc((size_t)N * 4);
    float* vvec   = (float*)alloc((size_t)N * 4);

    int nb = (N + 255) / 256;

    k_detect<<<1, 256, 0, stream>>>(ei, flag, gtails, NBC, accum);
    k_p1<<<(E + EPB - 1) / EPB, 256, 0, stream>>>(ei, E, N, NBC, flag, gtails, bb);
    k_p1b<<<1, 256, 0, stream>>>(gtails, N, NBC, boff, rowoff + N);
    k_p2<<<NBC, 256, 0, stream>>>(bb, gtails, boff, N, rowoff, dinv, colidx);
    k_val<<<nb, 256, 0, stream>>>(x, emb, N, valv);
    k_prepW<<<(KT_ALL * 4 * 64 * 8 + 255) / 256, 256, 0, stream>>>(W1, Wf);

    k_gemm1m<<<(N + 31) / 32, 128, 0, stream>>>(x, Wf, W1, valv, dinv, N, g1);

    // layer1 agg + W2 ; layer2 agg + W3 ; layer3 agg(+res) + W4 ; layer4 agg(+res) + W5
    k_fagg<64, 32, 0><<<(N + 7) / 8, 256, 0, stream>>>(g1, rowoff, colidx, dinv, b1, W2, N, g2, nullptr);
    k_fagg<32, 32, 0><<<(N + 15) / 16, 256, 0, stream>>>(g2, rowoff, colidx, dinv, b2, W3, N, g3, nullptr);
    k_fagg<32, 32, 1><<<(N + 15) / 16, 256, 0, stream>>>(g3, rowoff, colidx, dinv, b3, W4, N, g2, nullptr);
    k_fagg<32, 1, 1><<<(N + 15) / 16, 256, 0, stream>>>(g2, rowoff, colidx, dinv, b4, W5, N, nullptr, g5);

    k_agg1f<<<nb, 256, 0, stream>>>(g5, rowoff, colidx, dinv, b5, N, vvec);

    k_fc1<<<300, 128, 0, stream>>>(vvec, fc1W, N, accum);
    k_fc2<<<1, 128, 0, stream>>>(accum, fc1b, fc2W, fc2b, (float*)d_out);
}